// Round 1
// baseline (947.141 us; speedup 1.0000x reference)
//
#include <hip/hip_runtime.h>
#include <math.h>

// ---------------------------------------------------------------------------
// InvKin, fp32-VALU pipeline with bf16 z-materialization (R8).
// R7 pinned waves_per_eu(2,2) on heavy kernels (no spill, VGPR=116) but
// WRITE_SIZE stayed 603/620 MB vs 134 MB real and VALUBusy ~33%: the
// (2p,2p+1) row pairing + per-row [B][64] zbuf layout makes every store a
// 16B-per-lane write at 256B lane stride -> 64 partially-dirty 128B lines
// per instruction -> partial-line eviction (4.5x HBM write amplification,
// ~2.5 TB/s of pure overhead writes) + 8x L2 transaction amplification.
// R8: zbuf becomes 8 planes of [B]xuint4 (plane jb = units jb*8..jb*8+7),
// rows pair as (p, p+B/2). Every zbuf store/load is now 64 consecutive
// lanes x 16B = 1KiB fully-covered lines. k_colstats reworked for plane
// layout (16B/lane reads, register accumulators, shfl reduce). Per-row
// math is bit-identical to R7.
//   P1 k_stats_x : x second moments (layer-1 BN stats analytic)
//   P2 k_fin1    : fold BN1 -> fp32 W1p[64][3] + c1[64]
//   P3 k_z2      : h1 -> raw z2 -> bf16 planes   (rows p, p+B/2 per thread)
//   P4 k_colstats: per-unit sum/ssq of planes (one plane per 32-lane group)
//   P5 k_fin_bn  : s2,c2
//   P6 k_z3      : h2 = relu(s2*z2+c2); z3 = W3 h2 + b3 in place
//   P7 k_colstats: stats of z3
//   P8 k_fin_bn  : s3,c3
//   P9 k_final   : h3 -> head -> closed-form FK -> out
// Fallback path (small ws): exact R1 kernel set (verified PASS).
// ---------------------------------------------------------------------------

static constexpr float kEps = 1e-5f;

typedef __attribute__((ext_vector_type(2))) float f32x2;

#define HEAVY_BOUNDS __launch_bounds__(256) __attribute__((amdgpu_waves_per_eu(2, 2)))

// shared ws fp32 indices (both paths)
#define WS_STAT9 0
#define WS_SUM2  16
#define WS_SSQ2  80
#define WS_SUM3  144
#define WS_SSQ3  208
#define WS_W1P   288    // [64][3] fp32 (BN1-folded)
#define WS_C1    480    // [64]
// fast path only
#define FP_S2    8192
#define FP_C2    8256
#define FP_S3    8320
#define FP_C3    8384
// fallback (R1) only — may overlap FP_* since only one path ever runs
#define RC_W2P   544
#define RC_C2    4640
#define RC_W3P   4704
#define RC_C3    8800
// z buffer: byte offset 65536 (ushort index 32768)
#define ZB_U16   32768

__device__ __forceinline__ unsigned short f2bf(float f) {
  unsigned u = __builtin_bit_cast(unsigned, f);
  u += 0x7fffu + ((u >> 16) & 1u);
  return (unsigned short)(u >> 16);
}
__device__ __forceinline__ unsigned packbf2(float a, float b) {
  return (unsigned)f2bf(a) | ((unsigned)f2bf(b) << 16);
}
__device__ __forceinline__ void unpack2(unsigned w, float& lo, float& hi) {
  lo = __builtin_bit_cast(float, w << 16);
  hi = __builtin_bit_cast(float, w & 0xffff0000u);
}
__device__ __forceinline__ float bfbits(unsigned short s) {
  unsigned u = ((unsigned)s) << 16;
  return __builtin_bit_cast(float, u);
}
__device__ __forceinline__ f32x2 splat2(float v) {
  f32x2 r; r.x = v; r.y = v; return r;
}
__device__ __forceinline__ f32x2 vmax0(f32x2 v) {
  f32x2 r; r.x = fmaxf(v.x, 0.f); r.y = fmaxf(v.y, 0.f); return r;
}

__device__ __forceinline__ float wred64(float v) {
  v += __shfl_xor(v, 32, 64);
  v += __shfl_xor(v, 16, 64);
  v += __shfl_xor(v, 8, 64);
  v += __shfl_xor(v, 4, 64);
  v += __shfl_xor(v, 2, 64);
  v += __shfl_xor(v, 1, 64);
  return v;
}

// packed dual-row dot: (zA,zB) = sum_k w[k] * (hA[k],hB[k])
__device__ __forceinline__ f32x2 dot64v(const float* __restrict__ wr,
                                        const f32x2* __restrict__ h) {
  f32x2 a0 = splat2(0.f), a1 = splat2(0.f), a2 = splat2(0.f), a3 = splat2(0.f);
#pragma unroll
  for (int k = 0; k < 64; k += 4) {
    a0 += splat2(wr[k + 0]) * h[k + 0];
    a1 += splat2(wr[k + 1]) * h[k + 1];
    a2 += splat2(wr[k + 2]) * h[k + 2];
    a3 += splat2(wr[k + 3]) * h[k + 3];
  }
  return (a0 + a1) + (a2 + a3);
}

__device__ __forceinline__ float dot64(const float* __restrict__ wr,
                                       const float hin[64]) {
  float a0 = 0.f, a1 = 0.f, a2 = 0.f, a3 = 0.f;
#pragma unroll
  for (int k = 0; k < 64; k += 4) {
    a0 = fmaf(wr[k + 0], hin[k + 0], a0);
    a1 = fmaf(wr[k + 1], hin[k + 1], a1);
    a2 = fmaf(wr[k + 2], hin[k + 2], a2);
    a3 = fmaf(wr[k + 3], hin[k + 3], a3);
  }
  return (a0 + a1) + (a2 + a3);
}

// ---- P1: x second moments (shared) ---------------------------------------
__global__ void __launch_bounds__(256) k_stats_x(const float* __restrict__ x,
                                                 float* __restrict__ ws, int B) {
  int tid = blockIdx.x * 256 + threadIdx.x;
  int nt = gridDim.x * 256;
  float s0 = 0.f, s1 = 0.f, s2 = 0.f;
  float q00 = 0.f, q01 = 0.f, q02 = 0.f, q11 = 0.f, q12 = 0.f, q22 = 0.f;
  for (int r = tid; r < B; r += nt) {
    float x0 = x[3 * r], x1 = x[3 * r + 1], x2 = x[3 * r + 2];
    s0 += x0; s1 += x1; s2 += x2;
    q00 = fmaf(x0, x0, q00); q01 = fmaf(x0, x1, q01); q02 = fmaf(x0, x2, q02);
    q11 = fmaf(x1, x1, q11); q12 = fmaf(x1, x2, q12); q22 = fmaf(x2, x2, q22);
  }
  s0 = wred64(s0); s1 = wred64(s1); s2 = wred64(s2);
  q00 = wred64(q00); q01 = wred64(q01); q02 = wred64(q02);
  q11 = wred64(q11); q12 = wred64(q12); q22 = wred64(q22);
  __shared__ float part[9];
  if (threadIdx.x < 9) part[threadIdx.x] = 0.f;
  __syncthreads();
  if ((threadIdx.x & 63) == 0) {
    atomicAdd(&part[0], s0); atomicAdd(&part[1], s1); atomicAdd(&part[2], s2);
    atomicAdd(&part[3], q00); atomicAdd(&part[4], q01); atomicAdd(&part[5], q02);
    atomicAdd(&part[6], q11); atomicAdd(&part[7], q12); atomicAdd(&part[8], q22);
  }
  __syncthreads();
  if (threadIdx.x < 9) atomicAdd(&ws[WS_STAT9 + threadIdx.x], part[threadIdx.x]);
}

// ---- P2: fold BN1 (shared) ------------------------------------------------
__global__ void k_fin1(const float* __restrict__ W1, const float* __restrict__ b1,
                       const float* __restrict__ g1, const float* __restrict__ be1,
                       float* __restrict__ ws, int B) {
  int j = threadIdx.x;  // 64
  float inv = 1.0f / (float)B;
  float ex0 = ws[0] * inv, ex1 = ws[1] * inv, ex2 = ws[2] * inv;
  float c00 = ws[3] * inv - ex0 * ex0;
  float c01 = ws[4] * inv - ex0 * ex1;
  float c02 = ws[5] * inv - ex0 * ex2;
  float c11 = ws[6] * inv - ex1 * ex1;
  float c12 = ws[7] * inv - ex1 * ex2;
  float c22 = ws[8] * inv - ex2 * ex2;
  float w0 = W1[3 * j], w1 = W1[3 * j + 1], w2 = W1[3 * j + 2];
  float mean = w0 * ex0 + w1 * ex1 + w2 * ex2 + b1[j];
  float var = w0 * w0 * c00 + w1 * w1 * c11 + w2 * w2 * c22 +
              2.f * (w0 * w1 * c01 + w0 * w2 * c02 + w1 * w2 * c12);
  float s = g1[j] * rsqrtf(var + kEps);
  ws[WS_W1P + 3 * j + 0] = s * w0;
  ws[WS_W1P + 3 * j + 1] = s * w1;
  ws[WS_W1P + 3 * j + 2] = s * w2;
  ws[WS_C1 + j] = fmaf(s, b1[j] - mean, be1[j]);
}

// =========================== FAST PATH =====================================
// zbuf layout (R8): 8 planes; plane jb is [B] x uint4, holding bf16 z-values
// for units jb*8 .. jb*8+7 of every row (low16 of word = even unit).
// Row pairing: thread handles rows (p, p+npair); all plane accesses are
// 64-consecutive-lane x 16B = fully coalesced, full-line-covered.

// ---- P3: z2 = W2 h1 + b2 -> bf16 planes ----------------------------------
__global__ void HEAVY_BOUNDS k_z2(const float* __restrict__ x,
                                  const float* __restrict__ W2,
                                  const float* __restrict__ b2,
                                  const float* __restrict__ ws,
                                  unsigned short* __restrict__ zb, int B) {
  const float* W1p = ws + WS_W1P;
  const float* c1 = ws + WS_C1;
  uint4* __restrict__ zp = (uint4*)zb;
  int tid = blockIdx.x * 256 + threadIdx.x;
  int nt = gridDim.x * 256;
  int npair = (B + 1) >> 1;
  for (int p = tid; p < npair; p += nt) {
    int r0 = p;
    int r1 = (p + npair < B) ? (p + npair) : r0;
    f32x2 xv0, xv1, xv2;
    xv0.x = x[3 * r0];     xv0.y = x[3 * r1];
    xv1.x = x[3 * r0 + 1]; xv1.y = x[3 * r1 + 1];
    xv2.x = x[3 * r0 + 2]; xv2.y = x[3 * r1 + 2];
    f32x2 h[64];
#pragma unroll
    for (int k = 0; k < 64; ++k) {
      f32x2 z = splat2(c1[k]);
      z += splat2(W1p[3 * k + 0]) * xv0;
      z += splat2(W1p[3 * k + 1]) * xv1;
      z += splat2(W1p[3 * k + 2]) * xv2;
      h[k] = vmax0(z);
    }
#pragma unroll 1
    for (int jb = 0; jb < 8; ++jb) {
      f32x2 z[8];
#pragma unroll
      for (int u = 0; u < 8; ++u) {
        int j = jb * 8 + u;
        z[u] = dot64v(W2 + j * 64, h) + splat2(b2[j]);
      }
      uint4 oA, oB;
      oA.x = packbf2(z[0].x, z[1].x); oA.y = packbf2(z[2].x, z[3].x);
      oA.z = packbf2(z[4].x, z[5].x); oA.w = packbf2(z[6].x, z[7].x);
      oB.x = packbf2(z[0].y, z[1].y); oB.y = packbf2(z[2].y, z[3].y);
      oB.z = packbf2(z[4].y, z[5].y); oB.w = packbf2(z[6].y, z[7].y);
      zp[(size_t)jb * B + r0] = oA;
      zp[(size_t)jb * B + r1] = oB;
    }
  }
}

// ---- P4/P7: per-unit sum/ssq over planes ---------------------------------
// One plane per 32-lane group; 16B/lane coalesced reads; 8 register
// accumulators per thread; shfl-reduce within the group; 1 atomic per unit.
__global__ void __launch_bounds__(256) k_colstats(const unsigned short* __restrict__ zb,
                                                  float* __restrict__ sumg,
                                                  float* __restrict__ ssqg, int B) {
  const uint4* __restrict__ zp = (const uint4*)zb;
  int jb = threadIdx.x >> 5;   // 0..7 : plane (uniform per 32-lane half-wave)
  int rr = threadIdx.x & 31;
  const uint4* pl = zp + (size_t)jb * B;
  float accS[8], accQ[8];
#pragma unroll
  for (int u = 0; u < 8; ++u) { accS[u] = 0.f; accQ[u] = 0.f; }
  int rstep = gridDim.x * 32;
  for (int r = blockIdx.x * 32 + rr; r < B; r += rstep) {
    uint4 v = pl[r];
    float a, b;
    unpack2(v.x, a, b);
    accS[0] += a; accQ[0] = fmaf(a, a, accQ[0]);
    accS[1] += b; accQ[1] = fmaf(b, b, accQ[1]);
    unpack2(v.y, a, b);
    accS[2] += a; accQ[2] = fmaf(a, a, accQ[2]);
    accS[3] += b; accQ[3] = fmaf(b, b, accQ[3]);
    unpack2(v.z, a, b);
    accS[4] += a; accQ[4] = fmaf(a, a, accQ[4]);
    accS[5] += b; accQ[5] = fmaf(b, b, accQ[5]);
    unpack2(v.w, a, b);
    accS[6] += a; accQ[6] = fmaf(a, a, accQ[6]);
    accS[7] += b; accQ[7] = fmaf(b, b, accQ[7]);
  }
#pragma unroll
  for (int u = 0; u < 8; ++u) {
#pragma unroll
    for (int m = 1; m < 32; m <<= 1) {
      accS[u] += __shfl_xor(accS[u], m, 64);
      accQ[u] += __shfl_xor(accQ[u], m, 64);
    }
  }
  if (rr == 0) {
#pragma unroll
    for (int u = 0; u < 8; ++u) {
      atomicAdd(&sumg[jb * 8 + u], accS[u]);
      atomicAdd(&ssqg[jb * 8 + u], accQ[u]);
    }
  }
}

// ---- P5/P8: BN scale/shift only ------------------------------------------
__global__ void k_fin_bn(const float* __restrict__ sum, const float* __restrict__ ssq,
                         const float* __restrict__ g, const float* __restrict__ be,
                         float* __restrict__ sOut, float* __restrict__ cOut, int B) {
  int j = threadIdx.x;  // 64
  float inv = 1.0f / (float)B;
  float mean = sum[j] * inv;
  float var = ssq[j] * inv - mean * mean;
  float s = g[j] * rsqrtf(var + kEps);
  sOut[j] = s;
  cOut[j] = fmaf(-s, mean, be[j]);
}

// ---- P6: z3 = W3 relu(s2*z2+c2) + b3, in place ---------------------------
__global__ void HEAVY_BOUNDS k_z3(const float* __restrict__ W3,
                                  const float* __restrict__ b3,
                                  const float* __restrict__ ws,
                                  unsigned short* __restrict__ zb, int B) {
  const float* s2 = ws + FP_S2;
  const float* c2 = ws + FP_C2;
  uint4* __restrict__ zp = (uint4*)zb;
  int tid = blockIdx.x * 256 + threadIdx.x;
  int nt = gridDim.x * 256;
  int npair = (B + 1) >> 1;
  for (int p = tid; p < npair; p += nt) {
    int r0 = p;
    int r1 = (p + npair < B) ? (p + npair) : r0;
    f32x2 h[64];
#pragma unroll
    for (int jb = 0; jb < 8; ++jb) {
      uint4 vA = zp[(size_t)jb * B + r0];
      uint4 vB = zp[(size_t)jb * B + r1];
      float a0, a1, b0v, b1v;
      unpack2(vA.x, a0, a1); unpack2(vB.x, b0v, b1v);
      h[jb * 8 + 0].x = a0; h[jb * 8 + 0].y = b0v;
      h[jb * 8 + 1].x = a1; h[jb * 8 + 1].y = b1v;
      unpack2(vA.y, a0, a1); unpack2(vB.y, b0v, b1v);
      h[jb * 8 + 2].x = a0; h[jb * 8 + 2].y = b0v;
      h[jb * 8 + 3].x = a1; h[jb * 8 + 3].y = b1v;
      unpack2(vA.z, a0, a1); unpack2(vB.z, b0v, b1v);
      h[jb * 8 + 4].x = a0; h[jb * 8 + 4].y = b0v;
      h[jb * 8 + 5].x = a1; h[jb * 8 + 5].y = b1v;
      unpack2(vA.w, a0, a1); unpack2(vB.w, b0v, b1v);
      h[jb * 8 + 6].x = a0; h[jb * 8 + 6].y = b0v;
      h[jb * 8 + 7].x = a1; h[jb * 8 + 7].y = b1v;
    }
#pragma unroll
    for (int k = 0; k < 64; ++k)
      h[k] = vmax0(splat2(s2[k]) * h[k] + splat2(c2[k]));
#pragma unroll 1
    for (int jb = 0; jb < 8; ++jb) {
      f32x2 z[8];
#pragma unroll
      for (int u = 0; u < 8; ++u) {
        int j = jb * 8 + u;
        z[u] = dot64v(W3 + j * 64, h) + splat2(b3[j]);
      }
      uint4 oA, oB;
      oA.x = packbf2(z[0].x, z[1].x); oA.y = packbf2(z[2].x, z[3].x);
      oA.z = packbf2(z[4].x, z[5].x); oA.w = packbf2(z[6].x, z[7].x);
      oB.x = packbf2(z[0].y, z[1].y); oB.y = packbf2(z[2].y, z[3].y);
      oB.z = packbf2(z[4].y, z[5].y); oB.w = packbf2(z[6].y, z[7].y);
      zp[(size_t)jb * B + r0] = oA;
      zp[(size_t)jb * B + r1] = oB;
    }
  }
}

// ---- P9: h3 -> head -> FK -> out -----------------------------------------
__global__ void HEAVY_BOUNDS k_final_fast(const unsigned short* __restrict__ zb,
                                          const float* __restrict__ W4,
                                          const float* __restrict__ b4,
                                          const float* __restrict__ ws,
                                          float* __restrict__ out, int B) {
  const float* s3 = ws + FP_S3;
  const float* c3 = ws + FP_C3;
  const uint4* __restrict__ zp = (const uint4*)zb;
  int tid = blockIdx.x * 256 + threadIdx.x;
  int nt = gridDim.x * 256;
  int npair = (B + 1) >> 1;
  for (int p = tid; p < npair; p += nt) {
    int r0 = p;
    int r1 = (p + npair < B) ? (p + npair) : r0;
    f32x2 h[64];
#pragma unroll
    for (int jb = 0; jb < 8; ++jb) {
      uint4 vA = zp[(size_t)jb * B + r0];
      uint4 vB = zp[(size_t)jb * B + r1];
      float a0, a1, b0v, b1v;
      unpack2(vA.x, a0, a1); unpack2(vB.x, b0v, b1v);
      h[jb * 8 + 0].x = a0; h[jb * 8 + 0].y = b0v;
      h[jb * 8 + 1].x = a1; h[jb * 8 + 1].y = b1v;
      unpack2(vA.y, a0, a1); unpack2(vB.y, b0v, b1v);
      h[jb * 8 + 2].x = a0; h[jb * 8 + 2].y = b0v;
      h[jb * 8 + 3].x = a1; h[jb * 8 + 3].y = b1v;
      unpack2(vA.z, a0, a1); unpack2(vB.z, b0v, b1v);
      h[jb * 8 + 4].x = a0; h[jb * 8 + 4].y = b0v;
      h[jb * 8 + 5].x = a1; h[jb * 8 + 5].y = b1v;
      unpack2(vA.w, a0, a1); unpack2(vB.w, b0v, b1v);
      h[jb * 8 + 6].x = a0; h[jb * 8 + 6].y = b0v;
      h[jb * 8 + 7].x = a1; h[jb * 8 + 7].y = b1v;
    }
#pragma unroll
    for (int k = 0; k < 64; ++k)
      h[k] = vmax0(splat2(s3[k]) * h[k] + splat2(c3[k]));
    f32x2 t0 = dot64v(W4, h) + splat2(b4[0]);
    f32x2 t1 = dot64v(W4 + 64, h) + splat2(b4[1]);
    f32x2 t2 = dot64v(W4 + 128, h) + splat2(b4[2]);
    // row A
    {
      out[3 * r0 + 0] = t0.x;
      out[3 * r0 + 1] = t1.x;
      out[3 * r0 + 2] = t2.x;
      float s0, c0v, s1, c1v, s12, c12;
      sincosf(t0.x, &s0, &c0v);
      sincosf(t1.x, &s1, &c1v);
      sincosf(t1.x + t2.x, &s12, &c12);
      float A = fmaf(0.115f, c12, 0.12f * c1v);
      size_t o2 = (size_t)3 * B + 3 * r0;
      out[o2 + 0] = c0v * A;
      out[o2 + 1] = s0 * A;
      out[o2 + 2] = fmaf(0.115f, s12, 0.12f * s1);
    }
    if (r1 != r0) {
      out[3 * r1 + 0] = t0.y;
      out[3 * r1 + 1] = t1.y;
      out[3 * r1 + 2] = t2.y;
      float s0, c0v, s1, c1v, s12, c12;
      sincosf(t0.y, &s0, &c0v);
      sincosf(t1.y, &s1, &c1v);
      sincosf(t1.y + t2.y, &s12, &c12);
      float A = fmaf(0.115f, c12, 0.12f * c1v);
      size_t o2 = (size_t)3 * B + 3 * r1;
      out[o2 + 0] = c0v * A;
      out[o2 + 1] = s0 * A;
      out[o2 + 2] = fmaf(0.115f, s12, 0.12f * s1);
    }
  }
}

// ========================= FALLBACK (R1, verified) =========================

__device__ __forceinline__ void layer1_eval(const float* __restrict__ W1p,
                                            const float* __restrict__ c1,
                                            float x0, float x1, float x2,
                                            float h[64]) {
#pragma unroll
  for (int j = 0; j < 64; ++j) {
    float z = fmaf(W1p[3 * j + 2], x2,
               fmaf(W1p[3 * j + 1], x1, fmaf(W1p[3 * j], x0, c1[j])));
    h[j] = fmaxf(z, 0.f);
  }
}

__device__ __forceinline__ void dense_relu_rc(const float* __restrict__ Wp,
                                              const float* __restrict__ c,
                                              const float hin[64], float hout[64]) {
#pragma unroll
  for (int j = 0; j < 64; ++j)
    hout[j] = fmaxf(dot64(Wp + j * 64, hin) + c[j], 0.f);
}

__device__ __forceinline__ void dense_stats_rc(const float* __restrict__ W,
                                               const float* __restrict__ b,
                                               const float hin[64], int lane,
                                               float valid, float& accS, float& accQ) {
#pragma unroll 1
  for (int j = 0; j < 64; ++j) {
    float z = (dot64(W + j * 64, hin) + b[j]) * valid;
    float rs = wred64(z);
    float rq = wred64(z * z);
    accS += (lane == j) ? rs : 0.f;
    accQ += (lane == j) ? rq : 0.f;
  }
}

__device__ __forceinline__ void block_combine_rc(float accS, float accQ,
                                                 float* __restrict__ sumg,
                                                 float* __restrict__ ssqg) {
  __shared__ float sS[256], sQ[256];
  sS[threadIdx.x] = accS;
  sQ[threadIdx.x] = accQ;
  __syncthreads();
  if (threadIdx.x < 64) {
    float S = sS[threadIdx.x] + sS[threadIdx.x + 64] + sS[threadIdx.x + 128] + sS[threadIdx.x + 192];
    float Q = sQ[threadIdx.x] + sQ[threadIdx.x + 64] + sQ[threadIdx.x + 128] + sQ[threadIdx.x + 192];
    atomicAdd(&sumg[threadIdx.x], S);
    atomicAdd(&ssqg[threadIdx.x], Q);
  }
}

__global__ void __launch_bounds__(256) k_stats2_rc(const float* __restrict__ x,
                                                   const float* __restrict__ W2,
                                                   const float* __restrict__ b2,
                                                   float* __restrict__ ws, int B) {
  const float* W1p = ws + WS_W1P;
  const float* c1 = ws + WS_C1;
  int tid = blockIdx.x * 256 + threadIdx.x;
  int nt = gridDim.x * 256;
  int lane = threadIdx.x & 63;
  float accS = 0.f, accQ = 0.f;
  int iters = (B + nt - 1) / nt;
  for (int it = 0; it < iters; ++it) {
    int r = tid + it * nt;
    float valid = (r < B) ? 1.f : 0.f;
    int rc = (r < B) ? r : (B - 1);
    float h1[64];
    layer1_eval(W1p, c1, x[3 * rc], x[3 * rc + 1], x[3 * rc + 2], h1);
    dense_stats_rc(W2, b2, h1, lane, valid, accS, accQ);
  }
  block_combine_rc(accS, accQ, ws + WS_SUM2, ws + WS_SSQ2);
}

__global__ void k_fin_dense_rc(const float* __restrict__ W, const float* __restrict__ b,
                               const float* __restrict__ g, const float* __restrict__ be,
                               const float* __restrict__ sum, const float* __restrict__ ssq,
                               float* __restrict__ Wp, float* __restrict__ cc, int B) {
  int j = threadIdx.x;
  float inv = 1.0f / (float)B;
  float mean = sum[j] * inv;
  float var = ssq[j] * inv - mean * mean;
  float s = g[j] * rsqrtf(var + kEps);
  for (int k = 0; k < 64; ++k) Wp[j * 64 + k] = s * W[j * 64 + k];
  cc[j] = fmaf(s, b[j] - mean, be[j]);
}

__global__ void __launch_bounds__(256) k_stats3_rc(const float* __restrict__ x,
                                                   const float* __restrict__ W3,
                                                   const float* __restrict__ b3,
                                                   float* __restrict__ ws, int B) {
  const float* W1p = ws + WS_W1P;
  const float* c1 = ws + WS_C1;
  const float* W2p = ws + RC_W2P;
  const float* c2 = ws + RC_C2;
  int tid = blockIdx.x * 256 + threadIdx.x;
  int nt = gridDim.x * 256;
  int lane = threadIdx.x & 63;
  float accS = 0.f, accQ = 0.f;
  int iters = (B + nt - 1) / nt;
  for (int it = 0; it < iters; ++it) {
    int r = tid + it * nt;
    float valid = (r < B) ? 1.f : 0.f;
    int rc = (r < B) ? r : (B - 1);
    float h1[64], h2[64];
    layer1_eval(W1p, c1, x[3 * rc], x[3 * rc + 1], x[3 * rc + 2], h1);
    dense_relu_rc(W2p, c2, h1, h2);
    dense_stats_rc(W3, b3, h2, lane, valid, accS, accQ);
  }
  block_combine_rc(accS, accQ, ws + WS_SUM3, ws + WS_SSQ3);
}

__global__ void __launch_bounds__(256) k_final_rc(const float* __restrict__ x,
                                                  const float* __restrict__ W4,
                                                  const float* __restrict__ b4,
                                                  const float* __restrict__ ws,
                                                  float* __restrict__ out, int B) {
  const float* W1p = ws + WS_W1P;
  const float* c1 = ws + WS_C1;
  const float* W2p = ws + RC_W2P;
  const float* c2 = ws + RC_C2;
  const float* W3p = ws + RC_W3P;
  const float* c3 = ws + RC_C3;
  int tid = blockIdx.x * 256 + threadIdx.x;
  int nt = gridDim.x * 256;
  for (int r = tid; r < B; r += nt) {
    float h1[64], h2[64];
    layer1_eval(W1p, c1, x[3 * r], x[3 * r + 1], x[3 * r + 2], h1);
    dense_relu_rc(W2p, c2, h1, h2);
    float t0 = b4[0], t1 = b4[1], t2 = b4[2];
#pragma unroll 1
    for (int j = 0; j < 64; ++j) {
      float h3 = fmaxf(dot64(W3p + j * 64, h2) + c3[j], 0.f);
      t0 = fmaf(W4[j], h3, t0);
      t1 = fmaf(W4[64 + j], h3, t1);
      t2 = fmaf(W4[128 + j], h3, t2);
    }
    out[3 * r + 0] = t0;
    out[3 * r + 1] = t1;
    out[3 * r + 2] = t2;
    float s0, c0v, s1, c1v, s12, c12;
    sincosf(t0, &s0, &c0v);
    sincosf(t1, &s1, &c1v);
    sincosf(t1 + t2, &s12, &c12);
    float A = fmaf(0.115f, c12, 0.12f * c1v);
    size_t o2 = (size_t)3 * B + 3 * r;
    out[o2 + 0] = c0v * A;
    out[o2 + 1] = s0 * A;
    out[o2 + 2] = fmaf(0.115f, s12, 0.12f * s1);
  }
}

// ===========================================================================

extern "C" void kernel_launch(void* const* d_in, const int* in_sizes, int n_in,
                              void* d_out, int out_size, void* d_ws, size_t ws_size,
                              hipStream_t stream) {
  const float* x = (const float*)d_in[0];
  const float* W1 = (const float*)d_in[1];
  const float* b1 = (const float*)d_in[2];
  const float* g1 = (const float*)d_in[3];
  const float* be1 = (const float*)d_in[4];
  const float* W2 = (const float*)d_in[5];
  const float* b2 = (const float*)d_in[6];
  const float* g2 = (const float*)d_in[7];
  const float* be2 = (const float*)d_in[8];
  const float* W3 = (const float*)d_in[9];
  const float* b3 = (const float*)d_in[10];
  const float* g3 = (const float*)d_in[11];
  const float* be3 = (const float*)d_in[12];
  const float* W4 = (const float*)d_in[13];
  const float* b4 = (const float*)d_in[14];
  float* ws = (float*)d_ws;
  float* out = (float*)d_out;
  int B = in_sizes[0] / 3;

  hipMemsetAsync(d_ws, 0, 272 * sizeof(float), stream);

  const int blocks = 1024, thr = 256;
  const int zblocks = 2048;
  size_t need = 65536 + (size_t)B * 64 * 2;

  k_stats_x<<<blocks, thr, 0, stream>>>(x, ws, B);
  k_fin1<<<1, 64, 0, stream>>>(W1, b1, g1, be1, ws, B);

  if (ws_size >= need) {
    unsigned short* zb = (unsigned short*)ws + ZB_U16;
    k_z2<<<zblocks, thr, 0, stream>>>(x, W2, b2, ws, zb, B);
    k_colstats<<<blocks, thr, 0, stream>>>(zb, ws + WS_SUM2, ws + WS_SSQ2, B);
    k_fin_bn<<<1, 64, 0, stream>>>(ws + WS_SUM2, ws + WS_SSQ2, g2, be2,
                                   ws + FP_S2, ws + FP_C2, B);
    k_z3<<<zblocks, thr, 0, stream>>>(W3, b3, ws, zb, B);
    k_colstats<<<blocks, thr, 0, stream>>>(zb, ws + WS_SUM3, ws + WS_SSQ3, B);
    k_fin_bn<<<1, 64, 0, stream>>>(ws + WS_SUM3, ws + WS_SSQ3, g3, be3,
                                   ws + FP_S3, ws + FP_C3, B);
    k_final_fast<<<zblocks, thr, 0, stream>>>(zb, W4, b4, ws, out, B);
  } else {
    k_stats2_rc<<<blocks, thr, 0, stream>>>(x, W2, b2, ws, B);
    k_fin_dense_rc<<<1, 64, 0, stream>>>(W2, b2, g2, be2, ws + WS_SUM2, ws + WS_SSQ2,
                                         ws + RC_W2P, ws + RC_C2, B);
    k_stats3_rc<<<blocks, thr, 0, stream>>>(x, W3, b3, ws, B);
    k_fin_dense_rc<<<1, 64, 0, stream>>>(W3, b3, g3, be3, ws + WS_SUM3, ws + WS_SSQ3,
                                         ws + RC_W3P, ws + RC_C3, B);
    k_final_rc<<<blocks, thr, 0, stream>>>(x, W4, b4, ws, out, B);
  }
}

// Round 2
// 605.238 us; speedup vs baseline: 1.5649x; 1.5649x over previous
//
#include <hip/hip_runtime.h>
#include <math.h>

// ---------------------------------------------------------------------------
// InvKin, fp32-VALU pipeline with bf16 z-materialization (R9).
// R8 post-mortem: plane layout fixed write amplification exactly
// (WRITE 603->134 MB) but k_z2/k_z3 duration didn't move -> they are
// latency-bound at the pinned 2 waves/EU (VALUBusy ~37%, VALU floor ~80us
// of 223us), NOT store-bound. The regression was k_colstats: 218us x2 of
// pure stall (VALUBusy 2.2%) re-reading 134 MB the producers already had
// in registers.
// R9: fuse BN stats into the producers. k_z2/k_z3 wave-reduce per-unit
// sum/ssq of their z values in flight (wred64 butterfly + lane-indexed
// accumulator, the proven dense_stats_rc pattern), block-combine in LDS,
// one atomicAdd per unit per block. Both k_colstats dispatches deleted
// (-437us). Stats now exact fp32 (pre-bf16-rounding) - closer to ref.
// Heavy-kernel structure otherwise identical to R8 (plane zbuf, dual-row
// f32x2, waves_per_eu(2,2) AGPR-backed no-spill fit).
//   P1 k_stats_x : x second moments (layer-1 BN stats analytic)
//   P2 k_fin1    : fold BN1 -> fp32 W1p[64][3] + c1[64]
//   P3 k_z2      : h1 -> raw z2 -> bf16 planes + fused BN2 stats
//   P4 k_fin_bn  : s2,c2
//   P5 k_z3      : h2 = relu(s2*z2+c2); z3 = W3 h2 + b3 + fused BN3 stats
//   P6 k_fin_bn  : s3,c3
//   P7 k_final   : h3 -> head -> closed-form FK -> out
// Fallback path (small ws): exact R1 kernel set (verified PASS).
// ---------------------------------------------------------------------------

static constexpr float kEps = 1e-5f;

typedef __attribute__((ext_vector_type(2))) float f32x2;

#define HEAVY_BOUNDS __launch_bounds__(256) __attribute__((amdgpu_waves_per_eu(2, 2)))

// shared ws fp32 indices (both paths)
#define WS_STAT9 0
#define WS_SUM2  16
#define WS_SSQ2  80
#define WS_SUM3  144
#define WS_SSQ3  208
#define WS_W1P   288    // [64][3] fp32 (BN1-folded)
#define WS_C1    480    // [64]
// fast path only
#define FP_S2    8192
#define FP_C2    8256
#define FP_S3    8320
#define FP_C3    8384
// fallback (R1) only — may overlap FP_* since only one path ever runs
#define RC_W2P   544
#define RC_C2    4640
#define RC_W3P   4704
#define RC_C3    8800
// z buffer: byte offset 65536 (ushort index 32768)
#define ZB_U16   32768

__device__ __forceinline__ unsigned short f2bf(float f) {
  unsigned u = __builtin_bit_cast(unsigned, f);
  u += 0x7fffu + ((u >> 16) & 1u);
  return (unsigned short)(u >> 16);
}
__device__ __forceinline__ unsigned packbf2(float a, float b) {
  return (unsigned)f2bf(a) | ((unsigned)f2bf(b) << 16);
}
__device__ __forceinline__ void unpack2(unsigned w, float& lo, float& hi) {
  lo = __builtin_bit_cast(float, w << 16);
  hi = __builtin_bit_cast(float, w & 0xffff0000u);
}
__device__ __forceinline__ f32x2 splat2(float v) {
  f32x2 r; r.x = v; r.y = v; return r;
}
__device__ __forceinline__ f32x2 vmax0(f32x2 v) {
  f32x2 r; r.x = fmaxf(v.x, 0.f); r.y = fmaxf(v.y, 0.f); return r;
}

__device__ __forceinline__ float wred64(float v) {
  v += __shfl_xor(v, 32, 64);
  v += __shfl_xor(v, 16, 64);
  v += __shfl_xor(v, 8, 64);
  v += __shfl_xor(v, 4, 64);
  v += __shfl_xor(v, 2, 64);
  v += __shfl_xor(v, 1, 64);
  return v;
}

// packed dual-row dot: (zA,zB) = sum_k w[k] * (hA[k],hB[k])
__device__ __forceinline__ f32x2 dot64v(const float* __restrict__ wr,
                                        const f32x2* __restrict__ h) {
  f32x2 a0 = splat2(0.f), a1 = splat2(0.f), a2 = splat2(0.f), a3 = splat2(0.f);
#pragma unroll
  for (int k = 0; k < 64; k += 4) {
    a0 += splat2(wr[k + 0]) * h[k + 0];
    a1 += splat2(wr[k + 1]) * h[k + 1];
    a2 += splat2(wr[k + 2]) * h[k + 2];
    a3 += splat2(wr[k + 3]) * h[k + 3];
  }
  return (a0 + a1) + (a2 + a3);
}

__device__ __forceinline__ float dot64(const float* __restrict__ wr,
                                       const float hin[64]) {
  float a0 = 0.f, a1 = 0.f, a2 = 0.f, a3 = 0.f;
#pragma unroll
  for (int k = 0; k < 64; k += 4) {
    a0 = fmaf(wr[k + 0], hin[k + 0], a0);
    a1 = fmaf(wr[k + 1], hin[k + 1], a1);
    a2 = fmaf(wr[k + 2], hin[k + 2], a2);
    a3 = fmaf(wr[k + 3], hin[k + 3], a3);
  }
  return (a0 + a1) + (a2 + a3);
}

// fused BN stats: per jb-block of 8 units, wave-reduce sum/ssq of this
// thread's (up to) two rows; keep totals in the lane whose id == unit.
__device__ __forceinline__ void stat_accum8(const f32x2* __restrict__ z, int jb,
                                            int lane, float wB,
                                            float& sacc, float& qacc) {
#pragma unroll
  for (int u = 0; u < 8; ++u) {
    float s = z[u].x + wB * z[u].y;
    float q = fmaf(z[u].x, z[u].x, wB * z[u].y * z[u].y);
    s = wred64(s);
    q = wred64(q);
    int j = jb * 8 + u;
    sacc += (lane == j) ? s : 0.f;
    qacc += (lane == j) ? q : 0.f;
  }
}

__device__ __forceinline__ void block_combine_rc(float accS, float accQ,
                                                 float* __restrict__ sumg,
                                                 float* __restrict__ ssqg) {
  __shared__ float sS[256], sQ[256];
  sS[threadIdx.x] = accS;
  sQ[threadIdx.x] = accQ;
  __syncthreads();
  if (threadIdx.x < 64) {
    float S = sS[threadIdx.x] + sS[threadIdx.x + 64] + sS[threadIdx.x + 128] + sS[threadIdx.x + 192];
    float Q = sQ[threadIdx.x] + sQ[threadIdx.x + 64] + sQ[threadIdx.x + 128] + sQ[threadIdx.x + 192];
    atomicAdd(&sumg[threadIdx.x], S);
    atomicAdd(&ssqg[threadIdx.x], Q);
  }
}

// ---- P1: x second moments (shared) ---------------------------------------
__global__ void __launch_bounds__(256) k_stats_x(const float* __restrict__ x,
                                                 float* __restrict__ ws, int B) {
  int tid = blockIdx.x * 256 + threadIdx.x;
  int nt = gridDim.x * 256;
  float s0 = 0.f, s1 = 0.f, s2 = 0.f;
  float q00 = 0.f, q01 = 0.f, q02 = 0.f, q11 = 0.f, q12 = 0.f, q22 = 0.f;
  for (int r = tid; r < B; r += nt) {
    float x0 = x[3 * r], x1 = x[3 * r + 1], x2 = x[3 * r + 2];
    s0 += x0; s1 += x1; s2 += x2;
    q00 = fmaf(x0, x0, q00); q01 = fmaf(x0, x1, q01); q02 = fmaf(x0, x2, q02);
    q11 = fmaf(x1, x1, q11); q12 = fmaf(x1, x2, q12); q22 = fmaf(x2, x2, q22);
  }
  s0 = wred64(s0); s1 = wred64(s1); s2 = wred64(s2);
  q00 = wred64(q00); q01 = wred64(q01); q02 = wred64(q02);
  q11 = wred64(q11); q12 = wred64(q12); q22 = wred64(q22);
  __shared__ float part[9];
  if (threadIdx.x < 9) part[threadIdx.x] = 0.f;
  __syncthreads();
  if ((threadIdx.x & 63) == 0) {
    atomicAdd(&part[0], s0); atomicAdd(&part[1], s1); atomicAdd(&part[2], s2);
    atomicAdd(&part[3], q00); atomicAdd(&part[4], q01); atomicAdd(&part[5], q02);
    atomicAdd(&part[6], q11); atomicAdd(&part[7], q12); atomicAdd(&part[8], q22);
  }
  __syncthreads();
  if (threadIdx.x < 9) atomicAdd(&ws[WS_STAT9 + threadIdx.x], part[threadIdx.x]);
}

// ---- P2: fold BN1 (shared) ------------------------------------------------
__global__ void k_fin1(const float* __restrict__ W1, const float* __restrict__ b1,
                       const float* __restrict__ g1, const float* __restrict__ be1,
                       float* __restrict__ ws, int B) {
  int j = threadIdx.x;  // 64
  float inv = 1.0f / (float)B;
  float ex0 = ws[0] * inv, ex1 = ws[1] * inv, ex2 = ws[2] * inv;
  float c00 = ws[3] * inv - ex0 * ex0;
  float c01 = ws[4] * inv - ex0 * ex1;
  float c02 = ws[5] * inv - ex0 * ex2;
  float c11 = ws[6] * inv - ex1 * ex1;
  float c12 = ws[7] * inv - ex1 * ex2;
  float c22 = ws[8] * inv - ex2 * ex2;
  float w0 = W1[3 * j], w1 = W1[3 * j + 1], w2 = W1[3 * j + 2];
  float mean = w0 * ex0 + w1 * ex1 + w2 * ex2 + b1[j];
  float var = w0 * w0 * c00 + w1 * w1 * c11 + w2 * w2 * c22 +
              2.f * (w0 * w1 * c01 + w0 * w2 * c02 + w1 * w2 * c12);
  float s = g1[j] * rsqrtf(var + kEps);
  ws[WS_W1P + 3 * j + 0] = s * w0;
  ws[WS_W1P + 3 * j + 1] = s * w1;
  ws[WS_W1P + 3 * j + 2] = s * w2;
  ws[WS_C1 + j] = fmaf(s, b1[j] - mean, be1[j]);
}

// =========================== FAST PATH =====================================
// zbuf layout: 8 planes; plane jb is [B] x uint4, holding bf16 z-values for
// units jb*8 .. jb*8+7 of every row (low16 of word = even unit).
// Row pairing: thread handles rows (p, p+npair); all plane accesses are
// 64-consecutive-lane x 16B = fully coalesced, full-line-covered.

// ---- P3: z2 = W2 h1 + b2 -> bf16 planes + fused BN2 stats ----------------
__global__ void HEAVY_BOUNDS k_z2(const float* __restrict__ x,
                                  const float* __restrict__ W2,
                                  const float* __restrict__ b2,
                                  float* __restrict__ ws,
                                  unsigned short* __restrict__ zb, int B) {
  const float* W1p = ws + WS_W1P;
  const float* c1 = ws + WS_C1;
  uint4* __restrict__ zp = (uint4*)zb;
  int tid = blockIdx.x * 256 + threadIdx.x;
  int nt = gridDim.x * 256;
  int lane = threadIdx.x & 63;
  int npair = (B + 1) >> 1;
  float sacc = 0.f, qacc = 0.f;
  for (int p = tid; p < npair; p += nt) {
    int r0 = p;
    int r1 = (p + npair < B) ? (p + npair) : r0;
    float wB = (r1 != r0) ? 1.f : 0.f;
    f32x2 xv0, xv1, xv2;
    xv0.x = x[3 * r0];     xv0.y = x[3 * r1];
    xv1.x = x[3 * r0 + 1]; xv1.y = x[3 * r1 + 1];
    xv2.x = x[3 * r0 + 2]; xv2.y = x[3 * r1 + 2];
    f32x2 h[64];
#pragma unroll
    for (int k = 0; k < 64; ++k) {
      f32x2 z = splat2(c1[k]);
      z += splat2(W1p[3 * k + 0]) * xv0;
      z += splat2(W1p[3 * k + 1]) * xv1;
      z += splat2(W1p[3 * k + 2]) * xv2;
      h[k] = vmax0(z);
    }
#pragma unroll 1
    for (int jb = 0; jb < 8; ++jb) {
      f32x2 z[8];
#pragma unroll
      for (int u = 0; u < 8; ++u) {
        int j = jb * 8 + u;
        z[u] = dot64v(W2 + j * 64, h) + splat2(b2[j]);
      }
      stat_accum8(z, jb, lane, wB, sacc, qacc);
      uint4 oA, oB;
      oA.x = packbf2(z[0].x, z[1].x); oA.y = packbf2(z[2].x, z[3].x);
      oA.z = packbf2(z[4].x, z[5].x); oA.w = packbf2(z[6].x, z[7].x);
      oB.x = packbf2(z[0].y, z[1].y); oB.y = packbf2(z[2].y, z[3].y);
      oB.z = packbf2(z[4].y, z[5].y); oB.w = packbf2(z[6].y, z[7].y);
      zp[(size_t)jb * B + r0] = oA;
      zp[(size_t)jb * B + r1] = oB;
    }
  }
  block_combine_rc(sacc, qacc, ws + WS_SUM2, ws + WS_SSQ2);
}

// ---- P4/P6: BN scale/shift only ------------------------------------------
__global__ void k_fin_bn(const float* __restrict__ sum, const float* __restrict__ ssq,
                         const float* __restrict__ g, const float* __restrict__ be,
                         float* __restrict__ sOut, float* __restrict__ cOut, int B) {
  int j = threadIdx.x;  // 64
  float inv = 1.0f / (float)B;
  float mean = sum[j] * inv;
  float var = ssq[j] * inv - mean * mean;
  float s = g[j] * rsqrtf(var + kEps);
  sOut[j] = s;
  cOut[j] = fmaf(-s, mean, be[j]);
}

// ---- P5: z3 = W3 relu(s2*z2+c2) + b3, in place + fused BN3 stats ---------
__global__ void HEAVY_BOUNDS k_z3(const float* __restrict__ W3,
                                  const float* __restrict__ b3,
                                  float* __restrict__ ws,
                                  unsigned short* __restrict__ zb, int B) {
  const float* s2 = ws + FP_S2;
  const float* c2 = ws + FP_C2;
  uint4* __restrict__ zp = (uint4*)zb;
  int tid = blockIdx.x * 256 + threadIdx.x;
  int nt = gridDim.x * 256;
  int lane = threadIdx.x & 63;
  int npair = (B + 1) >> 1;
  float sacc = 0.f, qacc = 0.f;
  for (int p = tid; p < npair; p += nt) {
    int r0 = p;
    int r1 = (p + npair < B) ? (p + npair) : r0;
    float wB = (r1 != r0) ? 1.f : 0.f;
    f32x2 h[64];
#pragma unroll
    for (int jb = 0; jb < 8; ++jb) {
      uint4 vA = zp[(size_t)jb * B + r0];
      uint4 vB = zp[(size_t)jb * B + r1];
      float a0, a1, b0v, b1v;
      unpack2(vA.x, a0, a1); unpack2(vB.x, b0v, b1v);
      h[jb * 8 + 0].x = a0; h[jb * 8 + 0].y = b0v;
      h[jb * 8 + 1].x = a1; h[jb * 8 + 1].y = b1v;
      unpack2(vA.y, a0, a1); unpack2(vB.y, b0v, b1v);
      h[jb * 8 + 2].x = a0; h[jb * 8 + 2].y = b0v;
      h[jb * 8 + 3].x = a1; h[jb * 8 + 3].y = b1v;
      unpack2(vA.z, a0, a1); unpack2(vB.z, b0v, b1v);
      h[jb * 8 + 4].x = a0; h[jb * 8 + 4].y = b0v;
      h[jb * 8 + 5].x = a1; h[jb * 8 + 5].y = b1v;
      unpack2(vA.w, a0, a1); unpack2(vB.w, b0v, b1v);
      h[jb * 8 + 6].x = a0; h[jb * 8 + 6].y = b0v;
      h[jb * 8 + 7].x = a1; h[jb * 8 + 7].y = b1v;
    }
#pragma unroll
    for (int k = 0; k < 64; ++k)
      h[k] = vmax0(splat2(s2[k]) * h[k] + splat2(c2[k]));
#pragma unroll 1
    for (int jb = 0; jb < 8; ++jb) {
      f32x2 z[8];
#pragma unroll
      for (int u = 0; u < 8; ++u) {
        int j = jb * 8 + u;
        z[u] = dot64v(W3 + j * 64, h) + splat2(b3[j]);
      }
      stat_accum8(z, jb, lane, wB, sacc, qacc);
      uint4 oA, oB;
      oA.x = packbf2(z[0].x, z[1].x); oA.y = packbf2(z[2].x, z[3].x);
      oA.z = packbf2(z[4].x, z[5].x); oA.w = packbf2(z[6].x, z[7].x);
      oB.x = packbf2(z[0].y, z[1].y); oB.y = packbf2(z[2].y, z[3].y);
      oB.z = packbf2(z[4].y, z[5].y); oB.w = packbf2(z[6].y, z[7].y);
      zp[(size_t)jb * B + r0] = oA;
      zp[(size_t)jb * B + r1] = oB;
    }
  }
  block_combine_rc(sacc, qacc, ws + WS_SUM3, ws + WS_SSQ3);
}

// ---- P7: h3 -> head -> FK -> out -----------------------------------------
__global__ void HEAVY_BOUNDS k_final_fast(const unsigned short* __restrict__ zb,
                                          const float* __restrict__ W4,
                                          const float* __restrict__ b4,
                                          const float* __restrict__ ws,
                                          float* __restrict__ out, int B) {
  const float* s3 = ws + FP_S3;
  const float* c3 = ws + FP_C3;
  const uint4* __restrict__ zp = (const uint4*)zb;
  int tid = blockIdx.x * 256 + threadIdx.x;
  int nt = gridDim.x * 256;
  int npair = (B + 1) >> 1;
  for (int p = tid; p < npair; p += nt) {
    int r0 = p;
    int r1 = (p + npair < B) ? (p + npair) : r0;
    f32x2 h[64];
#pragma unroll
    for (int jb = 0; jb < 8; ++jb) {
      uint4 vA = zp[(size_t)jb * B + r0];
      uint4 vB = zp[(size_t)jb * B + r1];
      float a0, a1, b0v, b1v;
      unpack2(vA.x, a0, a1); unpack2(vB.x, b0v, b1v);
      h[jb * 8 + 0].x = a0; h[jb * 8 + 0].y = b0v;
      h[jb * 8 + 1].x = a1; h[jb * 8 + 1].y = b1v;
      unpack2(vA.y, a0, a1); unpack2(vB.y, b0v, b1v);
      h[jb * 8 + 2].x = a0; h[jb * 8 + 2].y = b0v;
      h[jb * 8 + 3].x = a1; h[jb * 8 + 3].y = b1v;
      unpack2(vA.z, a0, a1); unpack2(vB.z, b0v, b1v);
      h[jb * 8 + 4].x = a0; h[jb * 8 + 4].y = b0v;
      h[jb * 8 + 5].x = a1; h[jb * 8 + 5].y = b1v;
      unpack2(vA.w, a0, a1); unpack2(vB.w, b0v, b1v);
      h[jb * 8 + 6].x = a0; h[jb * 8 + 6].y = b0v;
      h[jb * 8 + 7].x = a1; h[jb * 8 + 7].y = b1v;
    }
#pragma unroll
    for (int k = 0; k < 64; ++k)
      h[k] = vmax0(splat2(s3[k]) * h[k] + splat2(c3[k]));
    f32x2 t0 = dot64v(W4, h) + splat2(b4[0]);
    f32x2 t1 = dot64v(W4 + 64, h) + splat2(b4[1]);
    f32x2 t2 = dot64v(W4 + 128, h) + splat2(b4[2]);
    // row A
    {
      out[3 * r0 + 0] = t0.x;
      out[3 * r0 + 1] = t1.x;
      out[3 * r0 + 2] = t2.x;
      float s0, c0v, s1, c1v, s12, c12;
      sincosf(t0.x, &s0, &c0v);
      sincosf(t1.x, &s1, &c1v);
      sincosf(t1.x + t2.x, &s12, &c12);
      float A = fmaf(0.115f, c12, 0.12f * c1v);
      size_t o2 = (size_t)3 * B + 3 * r0;
      out[o2 + 0] = c0v * A;
      out[o2 + 1] = s0 * A;
      out[o2 + 2] = fmaf(0.115f, s12, 0.12f * s1);
    }
    if (r1 != r0) {
      out[3 * r1 + 0] = t0.y;
      out[3 * r1 + 1] = t1.y;
      out[3 * r1 + 2] = t2.y;
      float s0, c0v, s1, c1v, s12, c12;
      sincosf(t0.y, &s0, &c0v);
      sincosf(t1.y, &s1, &c1v);
      sincosf(t1.y + t2.y, &s12, &c12);
      float A = fmaf(0.115f, c12, 0.12f * c1v);
      size_t o2 = (size_t)3 * B + 3 * r1;
      out[o2 + 0] = c0v * A;
      out[o2 + 1] = s0 * A;
      out[o2 + 2] = fmaf(0.115f, s12, 0.12f * s1);
    }
  }
}

// ========================= FALLBACK (R1, verified) =========================

__device__ __forceinline__ void layer1_eval(const float* __restrict__ W1p,
                                            const float* __restrict__ c1,
                                            float x0, float x1, float x2,
                                            float h[64]) {
#pragma unroll
  for (int j = 0; j < 64; ++j) {
    float z = fmaf(W1p[3 * j + 2], x2,
               fmaf(W1p[3 * j + 1], x1, fmaf(W1p[3 * j], x0, c1[j])));
    h[j] = fmaxf(z, 0.f);
  }
}

__device__ __forceinline__ void dense_relu_rc(const float* __restrict__ Wp,
                                              const float* __restrict__ c,
                                              const float hin[64], float hout[64]) {
#pragma unroll
  for (int j = 0; j < 64; ++j)
    hout[j] = fmaxf(dot64(Wp + j * 64, hin) + c[j], 0.f);
}

__device__ __forceinline__ void dense_stats_rc(const float* __restrict__ W,
                                               const float* __restrict__ b,
                                               const float hin[64], int lane,
                                               float valid, float& accS, float& accQ) {
#pragma unroll 1
  for (int j = 0; j < 64; ++j) {
    float z = (dot64(W + j * 64, hin) + b[j]) * valid;
    float rs = wred64(z);
    float rq = wred64(z * z);
    accS += (lane == j) ? rs : 0.f;
    accQ += (lane == j) ? rq : 0.f;
  }
}

__global__ void __launch_bounds__(256) k_stats2_rc(const float* __restrict__ x,
                                                   const float* __restrict__ W2,
                                                   const float* __restrict__ b2,
                                                   float* __restrict__ ws, int B) {
  const float* W1p = ws + WS_W1P;
  const float* c1 = ws + WS_C1;
  int tid = blockIdx.x * 256 + threadIdx.x;
  int nt = gridDim.x * 256;
  int lane = threadIdx.x & 63;
  float accS = 0.f, accQ = 0.f;
  int iters = (B + nt - 1) / nt;
  for (int it = 0; it < iters; ++it) {
    int r = tid + it * nt;
    float valid = (r < B) ? 1.f : 0.f;
    int rc = (r < B) ? r : (B - 1);
    float h1[64];
    layer1_eval(W1p, c1, x[3 * rc], x[3 * rc + 1], x[3 * rc + 2], h1);
    dense_stats_rc(W2, b2, h1, lane, valid, accS, accQ);
  }
  block_combine_rc(accS, accQ, ws + WS_SUM2, ws + WS_SSQ2);
}

__global__ void k_fin_dense_rc(const float* __restrict__ W, const float* __restrict__ b,
                               const float* __restrict__ g, const float* __restrict__ be,
                               const float* __restrict__ sum, const float* __restrict__ ssq,
                               float* __restrict__ Wp, float* __restrict__ cc, int B) {
  int j = threadIdx.x;
  float inv = 1.0f / (float)B;
  float mean = sum[j] * inv;
  float var = ssq[j] * inv - mean * mean;
  float s = g[j] * rsqrtf(var + kEps);
  for (int k = 0; k < 64; ++k) Wp[j * 64 + k] = s * W[j * 64 + k];
  cc[j] = fmaf(s, b[j] - mean, be[j]);
}

__global__ void __launch_bounds__(256) k_stats3_rc(const float* __restrict__ x,
                                                   const float* __restrict__ W3,
                                                   const float* __restrict__ b3,
                                                   float* __restrict__ ws, int B) {
  const float* W1p = ws + WS_W1P;
  const float* c1 = ws + WS_C1;
  const float* W2p = ws + RC_W2P;
  const float* c2 = ws + RC_C2;
  int tid = blockIdx.x * 256 + threadIdx.x;
  int nt = gridDim.x * 256;
  int lane = threadIdx.x & 63;
  float accS = 0.f, accQ = 0.f;
  int iters = (B + nt - 1) / nt;
  for (int it = 0; it < iters; ++it) {
    int r = tid + it * nt;
    float valid = (r < B) ? 1.f : 0.f;
    int rc = (r < B) ? r : (B - 1);
    float h1[64], h2[64];
    layer1_eval(W1p, c1, x[3 * rc], x[3 * rc + 1], x[3 * rc + 2], h1);
    dense_relu_rc(W2p, c2, h1, h2);
    dense_stats_rc(W3, b3, h2, lane, valid, accS, accQ);
  }
  block_combine_rc(accS, accQ, ws + WS_SUM3, ws + WS_SSQ3);
}

__global__ void __launch_bounds__(256) k_final_rc(const float* __restrict__ x,
                                                  const float* __restrict__ W4,
                                                  const float* __restrict__ b4,
                                                  const float* __restrict__ ws,
                                                  float* __restrict__ out, int B) {
  const float* W1p = ws + WS_W1P;
  const float* c1 = ws + WS_C1;
  const float* W2p = ws + RC_W2P;
  const float* c2 = ws + RC_C2;
  const float* W3p = ws + RC_W3P;
  const float* c3 = ws + RC_C3;
  int tid = blockIdx.x * 256 + threadIdx.x;
  int nt = gridDim.x * 256;
  for (int r = tid; r < B; r += nt) {
    float h1[64], h2[64];
    layer1_eval(W1p, c1, x[3 * r], x[3 * r + 1], x[3 * r + 2], h1);
    dense_relu_rc(W2p, c2, h1, h2);
    float t0 = b4[0], t1 = b4[1], t2 = b4[2];
#pragma unroll 1
    for (int j = 0; j < 64; ++j) {
      float h3 = fmaxf(dot64(W3p + j * 64, h2) + c3[j], 0.f);
      t0 = fmaf(W4[j], h3, t0);
      t1 = fmaf(W4[64 + j], h3, t1);
      t2 = fmaf(W4[128 + j], h3, t2);
    }
    out[3 * r + 0] = t0;
    out[3 * r + 1] = t1;
    out[3 * r + 2] = t2;
    float s0, c0v, s1, c1v, s12, c12;
    sincosf(t0, &s0, &c0v);
    sincosf(t1, &s1, &c1v);
    sincosf(t1 + t2, &s12, &c12);
    float A = fmaf(0.115f, c12, 0.12f * c1v);
    size_t o2 = (size_t)3 * B + 3 * r;
    out[o2 + 0] = c0v * A;
    out[o2 + 1] = s0 * A;
    out[o2 + 2] = fmaf(0.115f, s12, 0.12f * s1);
  }
}

// ===========================================================================

extern "C" void kernel_launch(void* const* d_in, const int* in_sizes, int n_in,
                              void* d_out, int out_size, void* d_ws, size_t ws_size,
                              hipStream_t stream) {
  const float* x = (const float*)d_in[0];
  const float* W1 = (const float*)d_in[1];
  const float* b1 = (const float*)d_in[2];
  const float* g1 = (const float*)d_in[3];
  const float* be1 = (const float*)d_in[4];
  const float* W2 = (const float*)d_in[5];
  const float* b2 = (const float*)d_in[6];
  const float* g2 = (const float*)d_in[7];
  const float* be2 = (const float*)d_in[8];
  const float* W3 = (const float*)d_in[9];
  const float* b3 = (const float*)d_in[10];
  const float* g3 = (const float*)d_in[11];
  const float* be3 = (const float*)d_in[12];
  const float* W4 = (const float*)d_in[13];
  const float* b4 = (const float*)d_in[14];
  float* ws = (float*)d_ws;
  float* out = (float*)d_out;
  int B = in_sizes[0] / 3;

  hipMemsetAsync(d_ws, 0, 272 * sizeof(float), stream);

  const int blocks = 1024, thr = 256;
  const int zblocks = 2048;
  size_t need = 65536 + (size_t)B * 64 * 2;

  k_stats_x<<<blocks, thr, 0, stream>>>(x, ws, B);
  k_fin1<<<1, 64, 0, stream>>>(W1, b1, g1, be1, ws, B);

  if (ws_size >= need) {
    unsigned short* zb = (unsigned short*)ws + ZB_U16;
    k_z2<<<zblocks, thr, 0, stream>>>(x, W2, b2, ws, zb, B);
    k_fin_bn<<<1, 64, 0, stream>>>(ws + WS_SUM2, ws + WS_SSQ2, g2, be2,
                                   ws + FP_S2, ws + FP_C2, B);
    k_z3<<<zblocks, thr, 0, stream>>>(W3, b3, ws, zb, B);
    k_fin_bn<<<1, 64, 0, stream>>>(ws + WS_SUM3, ws + WS_SSQ3, g3, be3,
                                   ws + FP_S3, ws + FP_C3, B);
    k_final_fast<<<zblocks, thr, 0, stream>>>(zb, W4, b4, ws, out, B);
  } else {
    k_stats2_rc<<<blocks, thr, 0, stream>>>(x, W2, b2, ws, B);
    k_fin_dense_rc<<<1, 64, 0, stream>>>(W2, b2, g2, be2, ws + WS_SUM2, ws + WS_SSQ2,
                                         ws + RC_W2P, ws + RC_C2, B);
    k_stats3_rc<<<blocks, thr, 0, stream>>>(x, W3, b3, ws, B);
    k_fin_dense_rc<<<1, 64, 0, stream>>>(W3, b3, g3, be3, ws + WS_SUM3, ws + WS_SSQ3,
                                         ws + RC_W3P, ws + RC_C3, B);
    k_final_rc<<<blocks, thr, 0, stream>>>(x, W4, b4, ws, out, B);
  }
}

// Round 3
// 529.180 us; speedup vs baseline: 1.7898x; 1.1437x over previous
//
#include <hip/hip_runtime.h>
#include <math.h>

// ---------------------------------------------------------------------------
// InvKin, fp32-VALU pipeline with bf16 z-materialization (R10).
// R9 post-mortem: fusing stats into producers worked (947->605us). Model
// revision: k_z2/k_z3 are VALU-THROUGHPUT-bound, not latency-bound —
// per-pair ~21k VALU-cycles x 8 sequential waves/SIMD matches the wall
// clock; R8's memory fix moved nothing and R9's +17% VALU moved +14%.
// (VALUBusy ~37% is a gfx94x-formula artifact.) So: cut instructions.
// R10:
//  (a) stats via 3-level butterfly reduce-scatter + 3-level all-reduce
//      (rs8): lane l ends up owning global unit index l (identity map,
//      block_combine unchanged). Per jb: 20 shuffles + ~76 VALU vs
//      96 shuffles + ~220 VALU of the 16x wred64 scheme.
//  (b) bf16 pack via v_cvt_pk_bf16_f32 (RNE == old manual f2bf): 1 instr
//      per packed word vs ~8 of hand bit-math.
// Numerics: identical bf16 rounding; stats reassociated only (ulp-level).
//   P1 k_stats_x : x second moments (layer-1 BN stats analytic)
//   P2 k_fin1    : fold BN1 -> fp32 W1p[64][3] + c1[64]
//   P3 k_z2      : h1 -> raw z2 -> bf16 planes + fused BN2 stats
//   P4 k_fin_bn  : s2,c2
//   P5 k_z3      : h2 = relu(s2*z2+c2); z3 = W3 h2 + b3 + fused BN3 stats
//   P6 k_fin_bn  : s3,c3
//   P7 k_final   : h3 -> head -> closed-form FK -> out
// Fallback path (small ws): exact R1 kernel set (verified PASS).
// ---------------------------------------------------------------------------

static constexpr float kEps = 1e-5f;

typedef __attribute__((ext_vector_type(2))) float f32x2;

#define HEAVY_BOUNDS __launch_bounds__(256) __attribute__((amdgpu_waves_per_eu(2, 2)))

// shared ws fp32 indices (both paths)
#define WS_STAT9 0
#define WS_SUM2  16
#define WS_SSQ2  80
#define WS_SUM3  144
#define WS_SSQ3  208
#define WS_W1P   288    // [64][3] fp32 (BN1-folded)
#define WS_C1    480    // [64]
// fast path only
#define FP_S2    8192
#define FP_C2    8256
#define FP_S3    8320
#define FP_C3    8384
// fallback (R1) only — may overlap FP_* since only one path ever runs
#define RC_W2P   544
#define RC_C2    4640
#define RC_W3P   4704
#define RC_C3    8800
// z buffer: byte offset 65536 (ushort index 32768)
#define ZB_U16   32768

// packed bf16x2 convert, round-to-nearest-even (matches old manual f2bf)
__device__ __forceinline__ unsigned packbf2(float a, float b) {
  unsigned r;
  asm("v_cvt_pk_bf16_f32 %0, %1, %2" : "=v"(r) : "v"(a), "v"(b));
  return r;
}
__device__ __forceinline__ void unpack2(unsigned w, float& lo, float& hi) {
  lo = __builtin_bit_cast(float, w << 16);
  hi = __builtin_bit_cast(float, w & 0xffff0000u);
}
__device__ __forceinline__ f32x2 splat2(float v) {
  f32x2 r; r.x = v; r.y = v; return r;
}
__device__ __forceinline__ f32x2 vmax0(f32x2 v) {
  f32x2 r; r.x = fmaxf(v.x, 0.f); r.y = fmaxf(v.y, 0.f); return r;
}

__device__ __forceinline__ float wred64(float v) {
  v += __shfl_xor(v, 32, 64);
  v += __shfl_xor(v, 16, 64);
  v += __shfl_xor(v, 8, 64);
  v += __shfl_xor(v, 4, 64);
  v += __shfl_xor(v, 2, 64);
  v += __shfl_xor(v, 1, 64);
  return v;
}

// butterfly reduce-scatter over 8 values: returns the full 64-lane sum of
// v[lane&7]. Levels 1/2/4 reduce-scatter the 8 units across the 8-lane
// group (lane keeps the unit whose bits match its low bits); levels
// 8/16/32 all-reduce the single survivor across the 8 groups.
__device__ __forceinline__ float rs8(const float* v, int lane) {
  int b0 = lane & 1, b1 = (lane >> 1) & 1, b2 = (lane >> 2) & 1;
  float r[4];
#pragma unroll
  for (int i = 0; i < 4; ++i) {
    float keep = b0 ? v[2 * i + 1] : v[2 * i];
    float send = b0 ? v[2 * i] : v[2 * i + 1];
    r[i] = keep + __shfl_xor(send, 1, 64);
  }
  float t[2];
#pragma unroll
  for (int i = 0; i < 2; ++i) {
    float keep = b1 ? r[2 * i + 1] : r[2 * i];
    float send = b1 ? r[2 * i] : r[2 * i + 1];
    t[i] = keep + __shfl_xor(send, 2, 64);
  }
  float keep = b2 ? t[1] : t[0];
  float send = b2 ? t[0] : t[1];
  float u = keep + __shfl_xor(send, 4, 64);
  u += __shfl_xor(u, 8, 64);
  u += __shfl_xor(u, 16, 64);
  u += __shfl_xor(u, 32, 64);
  return u;
}

// packed dual-row dot: (zA,zB) = sum_k w[k] * (hA[k],hB[k])
__device__ __forceinline__ f32x2 dot64v(const float* __restrict__ wr,
                                        const f32x2* __restrict__ h) {
  f32x2 a0 = splat2(0.f), a1 = splat2(0.f), a2 = splat2(0.f), a3 = splat2(0.f);
#pragma unroll
  for (int k = 0; k < 64; k += 4) {
    a0 += splat2(wr[k + 0]) * h[k + 0];
    a1 += splat2(wr[k + 1]) * h[k + 1];
    a2 += splat2(wr[k + 2]) * h[k + 2];
    a3 += splat2(wr[k + 3]) * h[k + 3];
  }
  return (a0 + a1) + (a2 + a3);
}

__device__ __forceinline__ float dot64(const float* __restrict__ wr,
                                       const float hin[64]) {
  float a0 = 0.f, a1 = 0.f, a2 = 0.f, a3 = 0.f;
#pragma unroll
  for (int k = 0; k < 64; k += 4) {
    a0 = fmaf(wr[k + 0], hin[k + 0], a0);
    a1 = fmaf(wr[k + 1], hin[k + 1], a1);
    a2 = fmaf(wr[k + 2], hin[k + 2], a2);
    a3 = fmaf(wr[k + 3], hin[k + 3], a3);
  }
  return (a0 + a1) + (a2 + a3);
}

// fused BN stats for one jb-block of 8 units via rs8.
// lane l accumulates global unit (l>>3)*8 + (l&7) == l  (identity map).
__device__ __forceinline__ void stat_rs8(const f32x2* __restrict__ z, int jb,
                                         int lane, float wB,
                                         float& sacc, float& qacc) {
  float s8[8], q8[8];
#pragma unroll
  for (int u = 0; u < 8; ++u) {
    s8[u] = z[u].x + wB * z[u].y;
    q8[u] = fmaf(z[u].x, z[u].x, wB * z[u].y * z[u].y);
  }
  float sv = rs8(s8, lane);
  float qv = rs8(q8, lane);
  if ((lane >> 3) == jb) {
    sacc += sv;
    qacc += qv;
  }
}

__device__ __forceinline__ void block_combine_rc(float accS, float accQ,
                                                 float* __restrict__ sumg,
                                                 float* __restrict__ ssqg) {
  __shared__ float sS[256], sQ[256];
  sS[threadIdx.x] = accS;
  sQ[threadIdx.x] = accQ;
  __syncthreads();
  if (threadIdx.x < 64) {
    float S = sS[threadIdx.x] + sS[threadIdx.x + 64] + sS[threadIdx.x + 128] + sS[threadIdx.x + 192];
    float Q = sQ[threadIdx.x] + sQ[threadIdx.x + 64] + sQ[threadIdx.x + 128] + sQ[threadIdx.x + 192];
    atomicAdd(&sumg[threadIdx.x], S);
    atomicAdd(&ssqg[threadIdx.x], Q);
  }
}

// ---- P1: x second moments (shared) ---------------------------------------
__global__ void __launch_bounds__(256) k_stats_x(const float* __restrict__ x,
                                                 float* __restrict__ ws, int B) {
  int tid = blockIdx.x * 256 + threadIdx.x;
  int nt = gridDim.x * 256;
  float s0 = 0.f, s1 = 0.f, s2 = 0.f;
  float q00 = 0.f, q01 = 0.f, q02 = 0.f, q11 = 0.f, q12 = 0.f, q22 = 0.f;
  for (int r = tid; r < B; r += nt) {
    float x0 = x[3 * r], x1 = x[3 * r + 1], x2 = x[3 * r + 2];
    s0 += x0; s1 += x1; s2 += x2;
    q00 = fmaf(x0, x0, q00); q01 = fmaf(x0, x1, q01); q02 = fmaf(x0, x2, q02);
    q11 = fmaf(x1, x1, q11); q12 = fmaf(x1, x2, q12); q22 = fmaf(x2, x2, q22);
  }
  s0 = wred64(s0); s1 = wred64(s1); s2 = wred64(s2);
  q00 = wred64(q00); q01 = wred64(q01); q02 = wred64(q02);
  q11 = wred64(q11); q12 = wred64(q12); q22 = wred64(q22);
  __shared__ float part[9];
  if (threadIdx.x < 9) part[threadIdx.x] = 0.f;
  __syncthreads();
  if ((threadIdx.x & 63) == 0) {
    atomicAdd(&part[0], s0); atomicAdd(&part[1], s1); atomicAdd(&part[2], s2);
    atomicAdd(&part[3], q00); atomicAdd(&part[4], q01); atomicAdd(&part[5], q02);
    atomicAdd(&part[6], q11); atomicAdd(&part[7], q12); atomicAdd(&part[8], q22);
  }
  __syncthreads();
  if (threadIdx.x < 9) atomicAdd(&ws[WS_STAT9 + threadIdx.x], part[threadIdx.x]);
}

// ---- P2: fold BN1 (shared) ------------------------------------------------
__global__ void k_fin1(const float* __restrict__ W1, const float* __restrict__ b1,
                       const float* __restrict__ g1, const float* __restrict__ be1,
                       float* __restrict__ ws, int B) {
  int j = threadIdx.x;  // 64
  float inv = 1.0f / (float)B;
  float ex0 = ws[0] * inv, ex1 = ws[1] * inv, ex2 = ws[2] * inv;
  float c00 = ws[3] * inv - ex0 * ex0;
  float c01 = ws[4] * inv - ex0 * ex1;
  float c02 = ws[5] * inv - ex0 * ex2;
  float c11 = ws[6] * inv - ex1 * ex1;
  float c12 = ws[7] * inv - ex1 * ex2;
  float c22 = ws[8] * inv - ex2 * ex2;
  float w0 = W1[3 * j], w1 = W1[3 * j + 1], w2 = W1[3 * j + 2];
  float mean = w0 * ex0 + w1 * ex1 + w2 * ex2 + b1[j];
  float var = w0 * w0 * c00 + w1 * w1 * c11 + w2 * w2 * c22 +
              2.f * (w0 * w1 * c01 + w0 * w2 * c02 + w1 * w2 * c12);
  float s = g1[j] * rsqrtf(var + kEps);
  ws[WS_W1P + 3 * j + 0] = s * w0;
  ws[WS_W1P + 3 * j + 1] = s * w1;
  ws[WS_W1P + 3 * j + 2] = s * w2;
  ws[WS_C1 + j] = fmaf(s, b1[j] - mean, be1[j]);
}

// =========================== FAST PATH =====================================
// zbuf layout: 8 planes; plane jb is [B] x uint4, holding bf16 z-values for
// units jb*8 .. jb*8+7 of every row (low16 of word = even unit).
// Row pairing: thread handles rows (p, p+npair); all plane accesses are
// 64-consecutive-lane x 16B = fully coalesced, full-line-covered.

// ---- P3: z2 = W2 h1 + b2 -> bf16 planes + fused BN2 stats ----------------
__global__ void HEAVY_BOUNDS k_z2(const float* __restrict__ x,
                                  const float* __restrict__ W2,
                                  const float* __restrict__ b2,
                                  float* __restrict__ ws,
                                  unsigned short* __restrict__ zb, int B) {
  const float* W1p = ws + WS_W1P;
  const float* c1 = ws + WS_C1;
  uint4* __restrict__ zp = (uint4*)zb;
  int tid = blockIdx.x * 256 + threadIdx.x;
  int nt = gridDim.x * 256;
  int lane = threadIdx.x & 63;
  int npair = (B + 1) >> 1;
  float sacc = 0.f, qacc = 0.f;
  for (int p = tid; p < npair; p += nt) {
    int r0 = p;
    int r1 = (p + npair < B) ? (p + npair) : r0;
    float wB = (r1 != r0) ? 1.f : 0.f;
    f32x2 xv0, xv1, xv2;
    xv0.x = x[3 * r0];     xv0.y = x[3 * r1];
    xv1.x = x[3 * r0 + 1]; xv1.y = x[3 * r1 + 1];
    xv2.x = x[3 * r0 + 2]; xv2.y = x[3 * r1 + 2];
    f32x2 h[64];
#pragma unroll
    for (int k = 0; k < 64; ++k) {
      f32x2 z = splat2(c1[k]);
      z += splat2(W1p[3 * k + 0]) * xv0;
      z += splat2(W1p[3 * k + 1]) * xv1;
      z += splat2(W1p[3 * k + 2]) * xv2;
      h[k] = vmax0(z);
    }
#pragma unroll 1
    for (int jb = 0; jb < 8; ++jb) {
      f32x2 z[8];
#pragma unroll
      for (int u = 0; u < 8; ++u) {
        int j = jb * 8 + u;
        z[u] = dot64v(W2 + j * 64, h) + splat2(b2[j]);
      }
      stat_rs8(z, jb, lane, wB, sacc, qacc);
      uint4 oA, oB;
      oA.x = packbf2(z[0].x, z[1].x); oA.y = packbf2(z[2].x, z[3].x);
      oA.z = packbf2(z[4].x, z[5].x); oA.w = packbf2(z[6].x, z[7].x);
      oB.x = packbf2(z[0].y, z[1].y); oB.y = packbf2(z[2].y, z[3].y);
      oB.z = packbf2(z[4].y, z[5].y); oB.w = packbf2(z[6].y, z[7].y);
      zp[(size_t)jb * B + r0] = oA;
      zp[(size_t)jb * B + r1] = oB;
    }
  }
  block_combine_rc(sacc, qacc, ws + WS_SUM2, ws + WS_SSQ2);
}

// ---- P4/P6: BN scale/shift only ------------------------------------------
__global__ void k_fin_bn(const float* __restrict__ sum, const float* __restrict__ ssq,
                         const float* __restrict__ g, const float* __restrict__ be,
                         float* __restrict__ sOut, float* __restrict__ cOut, int B) {
  int j = threadIdx.x;  // 64
  float inv = 1.0f / (float)B;
  float mean = sum[j] * inv;
  float var = ssq[j] * inv - mean * mean;
  float s = g[j] * rsqrtf(var + kEps);
  sOut[j] = s;
  cOut[j] = fmaf(-s, mean, be[j]);
}

// ---- P5: z3 = W3 relu(s2*z2+c2) + b3, in place + fused BN3 stats ---------
__global__ void HEAVY_BOUNDS k_z3(const float* __restrict__ W3,
                                  const float* __restrict__ b3,
                                  float* __restrict__ ws,
                                  unsigned short* __restrict__ zb, int B) {
  const float* s2 = ws + FP_S2;
  const float* c2 = ws + FP_C2;
  uint4* __restrict__ zp = (uint4*)zb;
  int tid = blockIdx.x * 256 + threadIdx.x;
  int nt = gridDim.x * 256;
  int lane = threadIdx.x & 63;
  int npair = (B + 1) >> 1;
  float sacc = 0.f, qacc = 0.f;
  for (int p = tid; p < npair; p += nt) {
    int r0 = p;
    int r1 = (p + npair < B) ? (p + npair) : r0;
    float wB = (r1 != r0) ? 1.f : 0.f;
    f32x2 h[64];
#pragma unroll
    for (int jb = 0; jb < 8; ++jb) {
      uint4 vA = zp[(size_t)jb * B + r0];
      uint4 vB = zp[(size_t)jb * B + r1];
      float a0, a1, b0v, b1v;
      unpack2(vA.x, a0, a1); unpack2(vB.x, b0v, b1v);
      h[jb * 8 + 0].x = a0; h[jb * 8 + 0].y = b0v;
      h[jb * 8 + 1].x = a1; h[jb * 8 + 1].y = b1v;
      unpack2(vA.y, a0, a1); unpack2(vB.y, b0v, b1v);
      h[jb * 8 + 2].x = a0; h[jb * 8 + 2].y = b0v;
      h[jb * 8 + 3].x = a1; h[jb * 8 + 3].y = b1v;
      unpack2(vA.z, a0, a1); unpack2(vB.z, b0v, b1v);
      h[jb * 8 + 4].x = a0; h[jb * 8 + 4].y = b0v;
      h[jb * 8 + 5].x = a1; h[jb * 8 + 5].y = b1v;
      unpack2(vA.w, a0, a1); unpack2(vB.w, b0v, b1v);
      h[jb * 8 + 6].x = a0; h[jb * 8 + 6].y = b0v;
      h[jb * 8 + 7].x = a1; h[jb * 8 + 7].y = b1v;
    }
#pragma unroll
    for (int k = 0; k < 64; ++k)
      h[k] = vmax0(splat2(s2[k]) * h[k] + splat2(c2[k]));
#pragma unroll 1
    for (int jb = 0; jb < 8; ++jb) {
      f32x2 z[8];
#pragma unroll
      for (int u = 0; u < 8; ++u) {
        int j = jb * 8 + u;
        z[u] = dot64v(W3 + j * 64, h) + splat2(b3[j]);
      }
      stat_rs8(z, jb, lane, wB, sacc, qacc);
      uint4 oA, oB;
      oA.x = packbf2(z[0].x, z[1].x); oA.y = packbf2(z[2].x, z[3].x);
      oA.z = packbf2(z[4].x, z[5].x); oA.w = packbf2(z[6].x, z[7].x);
      oB.x = packbf2(z[0].y, z[1].y); oB.y = packbf2(z[2].y, z[3].y);
      oB.z = packbf2(z[4].y, z[5].y); oB.w = packbf2(z[6].y, z[7].y);
      zp[(size_t)jb * B + r0] = oA;
      zp[(size_t)jb * B + r1] = oB;
    }
  }
  block_combine_rc(sacc, qacc, ws + WS_SUM3, ws + WS_SSQ3);
}

// ---- P7: h3 -> head -> FK -> out -----------------------------------------
__global__ void HEAVY_BOUNDS k_final_fast(const unsigned short* __restrict__ zb,
                                          const float* __restrict__ W4,
                                          const float* __restrict__ b4,
                                          const float* __restrict__ ws,
                                          float* __restrict__ out, int B) {
  const float* s3 = ws + FP_S3;
  const float* c3 = ws + FP_C3;
  const uint4* __restrict__ zp = (const uint4*)zb;
  int tid = blockIdx.x * 256 + threadIdx.x;
  int nt = gridDim.x * 256;
  int npair = (B + 1) >> 1;
  for (int p = tid; p < npair; p += nt) {
    int r0 = p;
    int r1 = (p + npair < B) ? (p + npair) : r0;
    f32x2 h[64];
#pragma unroll
    for (int jb = 0; jb < 8; ++jb) {
      uint4 vA = zp[(size_t)jb * B + r0];
      uint4 vB = zp[(size_t)jb * B + r1];
      float a0, a1, b0v, b1v;
      unpack2(vA.x, a0, a1); unpack2(vB.x, b0v, b1v);
      h[jb * 8 + 0].x = a0; h[jb * 8 + 0].y = b0v;
      h[jb * 8 + 1].x = a1; h[jb * 8 + 1].y = b1v;
      unpack2(vA.y, a0, a1); unpack2(vB.y, b0v, b1v);
      h[jb * 8 + 2].x = a0; h[jb * 8 + 2].y = b0v;
      h[jb * 8 + 3].x = a1; h[jb * 8 + 3].y = b1v;
      unpack2(vA.z, a0, a1); unpack2(vB.z, b0v, b1v);
      h[jb * 8 + 4].x = a0; h[jb * 8 + 4].y = b0v;
      h[jb * 8 + 5].x = a1; h[jb * 8 + 5].y = b1v;
      unpack2(vA.w, a0, a1); unpack2(vB.w, b0v, b1v);
      h[jb * 8 + 6].x = a0; h[jb * 8 + 6].y = b0v;
      h[jb * 8 + 7].x = a1; h[jb * 8 + 7].y = b1v;
    }
#pragma unroll
    for (int k = 0; k < 64; ++k)
      h[k] = vmax0(splat2(s3[k]) * h[k] + splat2(c3[k]));
    f32x2 t0 = dot64v(W4, h) + splat2(b4[0]);
    f32x2 t1 = dot64v(W4 + 64, h) + splat2(b4[1]);
    f32x2 t2 = dot64v(W4 + 128, h) + splat2(b4[2]);
    // row A
    {
      out[3 * r0 + 0] = t0.x;
      out[3 * r0 + 1] = t1.x;
      out[3 * r0 + 2] = t2.x;
      float s0, c0v, s1, c1v, s12, c12;
      sincosf(t0.x, &s0, &c0v);
      sincosf(t1.x, &s1, &c1v);
      sincosf(t1.x + t2.x, &s12, &c12);
      float A = fmaf(0.115f, c12, 0.12f * c1v);
      size_t o2 = (size_t)3 * B + 3 * r0;
      out[o2 + 0] = c0v * A;
      out[o2 + 1] = s0 * A;
      out[o2 + 2] = fmaf(0.115f, s12, 0.12f * s1);
    }
    if (r1 != r0) {
      out[3 * r1 + 0] = t0.y;
      out[3 * r1 + 1] = t1.y;
      out[3 * r1 + 2] = t2.y;
      float s0, c0v, s1, c1v, s12, c12;
      sincosf(t0.y, &s0, &c0v);
      sincosf(t1.y, &s1, &c1v);
      sincosf(t1.y + t2.y, &s12, &c12);
      float A = fmaf(0.115f, c12, 0.12f * c1v);
      size_t o2 = (size_t)3 * B + 3 * r1;
      out[o2 + 0] = c0v * A;
      out[o2 + 1] = s0 * A;
      out[o2 + 2] = fmaf(0.115f, s12, 0.12f * s1);
    }
  }
}

// ========================= FALLBACK (R1, verified) =========================

__device__ __forceinline__ void layer1_eval(const float* __restrict__ W1p,
                                            const float* __restrict__ c1,
                                            float x0, float x1, float x2,
                                            float h[64]) {
#pragma unroll
  for (int j = 0; j < 64; ++j) {
    float z = fmaf(W1p[3 * j + 2], x2,
               fmaf(W1p[3 * j + 1], x1, fmaf(W1p[3 * j], x0, c1[j])));
    h[j] = fmaxf(z, 0.f);
  }
}

__device__ __forceinline__ void dense_relu_rc(const float* __restrict__ Wp,
                                              const float* __restrict__ c,
                                              const float hin[64], float hout[64]) {
#pragma unroll
  for (int j = 0; j < 64; ++j)
    hout[j] = fmaxf(dot64(Wp + j * 64, hin) + c[j], 0.f);
}

__device__ __forceinline__ void dense_stats_rc(const float* __restrict__ W,
                                               const float* __restrict__ b,
                                               const float hin[64], int lane,
                                               float valid, float& accS, float& accQ) {
#pragma unroll 1
  for (int j = 0; j < 64; ++j) {
    float z = (dot64(W + j * 64, hin) + b[j]) * valid;
    float rs = wred64(z);
    float rq = wred64(z * z);
    accS += (lane == j) ? rs : 0.f;
    accQ += (lane == j) ? rq : 0.f;
  }
}

__global__ void __launch_bounds__(256) k_stats2_rc(const float* __restrict__ x,
                                                   const float* __restrict__ W2,
                                                   const float* __restrict__ b2,
                                                   float* __restrict__ ws, int B) {
  const float* W1p = ws + WS_W1P;
  const float* c1 = ws + WS_C1;
  int tid = blockIdx.x * 256 + threadIdx.x;
  int nt = gridDim.x * 256;
  int lane = threadIdx.x & 63;
  float accS = 0.f, accQ = 0.f;
  int iters = (B + nt - 1) / nt;
  for (int it = 0; it < iters; ++it) {
    int r = tid + it * nt;
    float valid = (r < B) ? 1.f : 0.f;
    int rc = (r < B) ? r : (B - 1);
    float h1[64];
    layer1_eval(W1p, c1, x[3 * rc], x[3 * rc + 1], x[3 * rc + 2], h1);
    dense_stats_rc(W2, b2, h1, lane, valid, accS, accQ);
  }
  block_combine_rc(accS, accQ, ws + WS_SUM2, ws + WS_SSQ2);
}

__global__ void k_fin_dense_rc(const float* __restrict__ W, const float* __restrict__ b,
                               const float* __restrict__ g, const float* __restrict__ be,
                               const float* __restrict__ sum, const float* __restrict__ ssq,
                               float* __restrict__ Wp, float* __restrict__ cc, int B) {
  int j = threadIdx.x;
  float inv = 1.0f / (float)B;
  float mean = sum[j] * inv;
  float var = ssq[j] * inv - mean * mean;
  float s = g[j] * rsqrtf(var + kEps);
  for (int k = 0; k < 64; ++k) Wp[j * 64 + k] = s * W[j * 64 + k];
  cc[j] = fmaf(s, b[j] - mean, be[j]);
}

__global__ void __launch_bounds__(256) k_stats3_rc(const float* __restrict__ x,
                                                   const float* __restrict__ W3,
                                                   const float* __restrict__ b3,
                                                   float* __restrict__ ws, int B) {
  const float* W1p = ws + WS_W1P;
  const float* c1 = ws + WS_C1;
  const float* W2p = ws + RC_W2P;
  const float* c2 = ws + RC_C2;
  int tid = blockIdx.x * 256 + threadIdx.x;
  int nt = gridDim.x * 256;
  int lane = threadIdx.x & 63;
  float accS = 0.f, accQ = 0.f;
  int iters = (B + nt - 1) / nt;
  for (int it = 0; it < iters; ++it) {
    int r = tid + it * nt;
    float valid = (r < B) ? 1.f : 0.f;
    int rc = (r < B) ? r : (B - 1);
    float h1[64], h2[64];
    layer1_eval(W1p, c1, x[3 * rc], x[3 * rc + 1], x[3 * rc + 2], h1);
    dense_relu_rc(W2p, c2, h1, h2);
    dense_stats_rc(W3, b3, h2, lane, valid, accS, accQ);
  }
  block_combine_rc(accS, accQ, ws + WS_SUM3, ws + WS_SSQ3);
}

__global__ void __launch_bounds__(256) k_final_rc(const float* __restrict__ x,
                                                  const float* __restrict__ W4,
                                                  const float* __restrict__ b4,
                                                  const float* __restrict__ ws,
                                                  float* __restrict__ out, int B) {
  const float* W1p = ws + WS_W1P;
  const float* c1 = ws + WS_C1;
  const float* W2p = ws + RC_W2P;
  const float* c2 = ws + RC_C2;
  const float* W3p = ws + RC_W3P;
  const float* c3 = ws + RC_C3;
  int tid = blockIdx.x * 256 + threadIdx.x;
  int nt = gridDim.x * 256;
  for (int r = tid; r < B; r += nt) {
    float h1[64], h2[64];
    layer1_eval(W1p, c1, x[3 * r], x[3 * r + 1], x[3 * r + 2], h1);
    dense_relu_rc(W2p, c2, h1, h2);
    float t0 = b4[0], t1 = b4[1], t2 = b4[2];
#pragma unroll 1
    for (int j = 0; j < 64; ++j) {
      float h3 = fmaxf(dot64(W3p + j * 64, h2) + c3[j], 0.f);
      t0 = fmaf(W4[j], h3, t0);
      t1 = fmaf(W4[64 + j], h3, t1);
      t2 = fmaf(W4[128 + j], h3, t2);
    }
    out[3 * r + 0] = t0;
    out[3 * r + 1] = t1;
    out[3 * r + 2] = t2;
    float s0, c0v, s1, c1v, s12, c12;
    sincosf(t0, &s0, &c0v);
    sincosf(t1, &s1, &c1v);
    sincosf(t1 + t2, &s12, &c12);
    float A = fmaf(0.115f, c12, 0.12f * c1v);
    size_t o2 = (size_t)3 * B + 3 * r;
    out[o2 + 0] = c0v * A;
    out[o2 + 1] = s0 * A;
    out[o2 + 2] = fmaf(0.115f, s12, 0.12f * s1);
  }
}

// ===========================================================================

extern "C" void kernel_launch(void* const* d_in, const int* in_sizes, int n_in,
                              void* d_out, int out_size, void* d_ws, size_t ws_size,
                              hipStream_t stream) {
  const float* x = (const float*)d_in[0];
  const float* W1 = (const float*)d_in[1];
  const float* b1 = (const float*)d_in[2];
  const float* g1 = (const float*)d_in[3];
  const float* be1 = (const float*)d_in[4];
  const float* W2 = (const float*)d_in[5];
  const float* b2 = (const float*)d_in[6];
  const float* g2 = (const float*)d_in[7];
  const float* be2 = (const float*)d_in[8];
  const float* W3 = (const float*)d_in[9];
  const float* b3 = (const float*)d_in[10];
  const float* g3 = (const float*)d_in[11];
  const float* be3 = (const float*)d_in[12];
  const float* W4 = (const float*)d_in[13];
  const float* b4 = (const float*)d_in[14];
  float* ws = (float*)d_ws;
  float* out = (float*)d_out;
  int B = in_sizes[0] / 3;

  hipMemsetAsync(d_ws, 0, 272 * sizeof(float), stream);

  const int blocks = 1024, thr = 256;
  const int zblocks = 2048;
  size_t need = 65536 + (size_t)B * 64 * 2;

  k_stats_x<<<blocks, thr, 0, stream>>>(x, ws, B);
  k_fin1<<<1, 64, 0, stream>>>(W1, b1, g1, be1, ws, B);

  if (ws_size >= need) {
    unsigned short* zb = (unsigned short*)ws + ZB_U16;
    k_z2<<<zblocks, thr, 0, stream>>>(x, W2, b2, ws, zb, B);
    k_fin_bn<<<1, 64, 0, stream>>>(ws + WS_SUM2, ws + WS_SSQ2, g2, be2,
                                   ws + FP_S2, ws + FP_C2, B);
    k_z3<<<zblocks, thr, 0, stream>>>(W3, b3, ws, zb, B);
    k_fin_bn<<<1, 64, 0, stream>>>(ws + WS_SUM3, ws + WS_SSQ3, g3, be3,
                                   ws + FP_S3, ws + FP_C3, B);
    k_final_fast<<<zblocks, thr, 0, stream>>>(zb, W4, b4, ws, out, B);
  } else {
    k_stats2_rc<<<blocks, thr, 0, stream>>>(x, W2, b2, ws, B);
    k_fin_dense_rc<<<1, 64, 0, stream>>>(W2, b2, g2, be2, ws + WS_SUM2, ws + WS_SSQ2,
                                         ws + RC_W2P, ws + RC_C2, B);
    k_stats3_rc<<<blocks, thr, 0, stream>>>(x, W3, b3, ws, B);
    k_fin_dense_rc<<<1, 64, 0, stream>>>(W3, b3, g3, be3, ws + WS_SUM3, ws + WS_SSQ3,
                                         ws + RC_W3P, ws + RC_C3, B);
    k_final_rc<<<blocks, thr, 0, stream>>>(x, W4, b4, ws, out, B);
  }
}

// Round 4
// 489.220 us; speedup vs baseline: 1.9360x; 1.0817x over previous
//
#include <hip/hip_runtime.h>
#include <math.h>

// ---------------------------------------------------------------------------
// InvKin, fp32-VALU pipeline with bf16 z-materialization (R11).
// R10 post-mortem: instr cuts helped (605->529) but sub-linearly. Refined
// model: VALUBusy 37% is REAL (scalarized f32x2 recount ~= 75us busy
// matches counter); wall = 3x busy -> heavies are ISSUE/LATENCY-limited at
// the pinned 2 waves/EU. The pin existed only because dual-row h[64] f32x2
// = 128 regs forced an AGPR-backed fit (VGPR_Count=116 < 128 proves h is
// in AGPRs). The dual-row structure is now the bottleneck.
// R11: single-row threads. h[64] plain f32 = 64 VGPR; total ~110 VGPR ->
// 4 waves/EU, no AGPR, no spill. Per-row instr ~= scalarized dual-row, but
// 2x resident waves for latency hiding. Stats: R10 rs8+gate on scalar z
// (s8 = w*z, q8 = s8*z), shuffle-safe tail via iters/valid pattern.
// waves_per_eu(3,4): >=3 guaranteed (no forced spill), allocator hits 4.
//   P1 k_stats_x : x second moments (layer-1 BN stats analytic)
//   P2 k_fin1    : fold BN1 -> fp32 W1p[64][3] + c1[64]
//   P3 k_z2      : h1 -> raw z2 -> bf16 planes + fused BN2 stats
//   P4 k_fin_bn  : s2,c2
//   P5 k_z3      : h2 = relu(s2*z2+c2); z3 = W3 h2 + b3 + fused BN3 stats
//   P6 k_fin_bn  : s3,c3
//   P7 k_final   : h3 -> head -> closed-form FK -> out
// Fallback path (small ws): exact R1 kernel set (verified PASS).
// ---------------------------------------------------------------------------

static constexpr float kEps = 1e-5f;

#define HEAVY_BOUNDS __launch_bounds__(256) __attribute__((amdgpu_waves_per_eu(3, 4)))

// shared ws fp32 indices (both paths)
#define WS_STAT9 0
#define WS_SUM2  16
#define WS_SSQ2  80
#define WS_SUM3  144
#define WS_SSQ3  208
#define WS_W1P   288    // [64][3] fp32 (BN1-folded)
#define WS_C1    480    // [64]
// fast path only
#define FP_S2    8192
#define FP_C2    8256
#define FP_S3    8320
#define FP_C3    8384
// fallback (R1) only — may overlap FP_* since only one path ever runs
#define RC_W2P   544
#define RC_C2    4640
#define RC_W3P   4704
#define RC_C3    8800
// z buffer: byte offset 65536 (ushort index 32768)
#define ZB_U16   32768

// packed bf16x2 convert, round-to-nearest-even
__device__ __forceinline__ unsigned packbf2(float a, float b) {
  unsigned r;
  asm("v_cvt_pk_bf16_f32 %0, %1, %2" : "=v"(r) : "v"(a), "v"(b));
  return r;
}
__device__ __forceinline__ void unpack2(unsigned w, float& lo, float& hi) {
  lo = __builtin_bit_cast(float, w << 16);
  hi = __builtin_bit_cast(float, w & 0xffff0000u);
}

__device__ __forceinline__ float wred64(float v) {
  v += __shfl_xor(v, 32, 64);
  v += __shfl_xor(v, 16, 64);
  v += __shfl_xor(v, 8, 64);
  v += __shfl_xor(v, 4, 64);
  v += __shfl_xor(v, 2, 64);
  v += __shfl_xor(v, 1, 64);
  return v;
}

// butterfly reduce-scatter over 8 values: returns the full 64-lane sum of
// v[lane&7]. Levels 1/2/4 reduce-scatter the 8 units across the 8-lane
// group; levels 8/16/32 all-reduce the survivor across the 8 groups.
__device__ __forceinline__ float rs8(const float* v, int lane) {
  int b0 = lane & 1, b1 = (lane >> 1) & 1, b2 = (lane >> 2) & 1;
  float r[4];
#pragma unroll
  for (int i = 0; i < 4; ++i) {
    float keep = b0 ? v[2 * i + 1] : v[2 * i];
    float send = b0 ? v[2 * i] : v[2 * i + 1];
    r[i] = keep + __shfl_xor(send, 1, 64);
  }
  float t[2];
#pragma unroll
  for (int i = 0; i < 2; ++i) {
    float keep = b1 ? r[2 * i + 1] : r[2 * i];
    float send = b1 ? r[2 * i] : r[2 * i + 1];
    t[i] = keep + __shfl_xor(send, 2, 64);
  }
  float keep = b2 ? t[1] : t[0];
  float send = b2 ? t[0] : t[1];
  float u = keep + __shfl_xor(send, 4, 64);
  u += __shfl_xor(u, 8, 64);
  u += __shfl_xor(u, 16, 64);
  u += __shfl_xor(u, 32, 64);
  return u;
}

__device__ __forceinline__ float dot64(const float* __restrict__ wr,
                                       const float hin[64]) {
  float a0 = 0.f, a1 = 0.f, a2 = 0.f, a3 = 0.f;
#pragma unroll
  for (int k = 0; k < 64; k += 4) {
    a0 = fmaf(wr[k + 0], hin[k + 0], a0);
    a1 = fmaf(wr[k + 1], hin[k + 1], a1);
    a2 = fmaf(wr[k + 2], hin[k + 2], a2);
    a3 = fmaf(wr[k + 3], hin[k + 3], a3);
  }
  return (a0 + a1) + (a2 + a3);
}

// fused BN stats for one jb-block of 8 units, scalar-z form.
// lane l accumulates global unit (l>>3)*8 + (l&7) == l  (identity map).
__device__ __forceinline__ void stat_rs8s(const float* __restrict__ z, int jb,
                                          int lane, float w,
                                          float& sacc, float& qacc) {
  float s8[8], q8[8];
#pragma unroll
  for (int u = 0; u < 8; ++u) {
    s8[u] = w * z[u];
    q8[u] = s8[u] * z[u];
  }
  float sv = rs8(s8, lane);
  float qv = rs8(q8, lane);
  if ((lane >> 3) == jb) {
    sacc += sv;
    qacc += qv;
  }
}

__device__ __forceinline__ void block_combine_rc(float accS, float accQ,
                                                 float* __restrict__ sumg,
                                                 float* __restrict__ ssqg) {
  __shared__ float sS[256], sQ[256];
  sS[threadIdx.x] = accS;
  sQ[threadIdx.x] = accQ;
  __syncthreads();
  if (threadIdx.x < 64) {
    float S = sS[threadIdx.x] + sS[threadIdx.x + 64] + sS[threadIdx.x + 128] + sS[threadIdx.x + 192];
    float Q = sQ[threadIdx.x] + sQ[threadIdx.x + 64] + sQ[threadIdx.x + 128] + sQ[threadIdx.x + 192];
    atomicAdd(&sumg[threadIdx.x], S);
    atomicAdd(&ssqg[threadIdx.x], Q);
  }
}

// ---- P1: x second moments (shared) ---------------------------------------
__global__ void __launch_bounds__(256) k_stats_x(const float* __restrict__ x,
                                                 float* __restrict__ ws, int B) {
  int tid = blockIdx.x * 256 + threadIdx.x;
  int nt = gridDim.x * 256;
  float s0 = 0.f, s1 = 0.f, s2 = 0.f;
  float q00 = 0.f, q01 = 0.f, q02 = 0.f, q11 = 0.f, q12 = 0.f, q22 = 0.f;
  for (int r = tid; r < B; r += nt) {
    float x0 = x[3 * r], x1 = x[3 * r + 1], x2 = x[3 * r + 2];
    s0 += x0; s1 += x1; s2 += x2;
    q00 = fmaf(x0, x0, q00); q01 = fmaf(x0, x1, q01); q02 = fmaf(x0, x2, q02);
    q11 = fmaf(x1, x1, q11); q12 = fmaf(x1, x2, q12); q22 = fmaf(x2, x2, q22);
  }
  s0 = wred64(s0); s1 = wred64(s1); s2 = wred64(s2);
  q00 = wred64(q00); q01 = wred64(q01); q02 = wred64(q02);
  q11 = wred64(q11); q12 = wred64(q12); q22 = wred64(q22);
  __shared__ float part[9];
  if (threadIdx.x < 9) part[threadIdx.x] = 0.f;
  __syncthreads();
  if ((threadIdx.x & 63) == 0) {
    atomicAdd(&part[0], s0); atomicAdd(&part[1], s1); atomicAdd(&part[2], s2);
    atomicAdd(&part[3], q00); atomicAdd(&part[4], q01); atomicAdd(&part[5], q02);
    atomicAdd(&part[6], q11); atomicAdd(&part[7], q12); atomicAdd(&part[8], q22);
  }
  __syncthreads();
  if (threadIdx.x < 9) atomicAdd(&ws[WS_STAT9 + threadIdx.x], part[threadIdx.x]);
}

// ---- P2: fold BN1 (shared) ------------------------------------------------
__global__ void k_fin1(const float* __restrict__ W1, const float* __restrict__ b1,
                       const float* __restrict__ g1, const float* __restrict__ be1,
                       float* __restrict__ ws, int B) {
  int j = threadIdx.x;  // 64
  float inv = 1.0f / (float)B;
  float ex0 = ws[0] * inv, ex1 = ws[1] * inv, ex2 = ws[2] * inv;
  float c00 = ws[3] * inv - ex0 * ex0;
  float c01 = ws[4] * inv - ex0 * ex1;
  float c02 = ws[5] * inv - ex0 * ex2;
  float c11 = ws[6] * inv - ex1 * ex1;
  float c12 = ws[7] * inv - ex1 * ex2;
  float c22 = ws[8] * inv - ex2 * ex2;
  float w0 = W1[3 * j], w1 = W1[3 * j + 1], w2 = W1[3 * j + 2];
  float mean = w0 * ex0 + w1 * ex1 + w2 * ex2 + b1[j];
  float var = w0 * w0 * c00 + w1 * w1 * c11 + w2 * w2 * c22 +
              2.f * (w0 * w1 * c01 + w0 * w2 * c02 + w1 * w2 * c12);
  float s = g1[j] * rsqrtf(var + kEps);
  ws[WS_W1P + 3 * j + 0] = s * w0;
  ws[WS_W1P + 3 * j + 1] = s * w1;
  ws[WS_W1P + 3 * j + 2] = s * w2;
  ws[WS_C1 + j] = fmaf(s, b1[j] - mean, be1[j]);
}

// =========================== FAST PATH =====================================
// zbuf layout: 8 planes; plane jb is [B] x uint4, holding bf16 z-values for
// units jb*8 .. jb*8+7 of every row (low16 of word = even unit).
// Single row per thread; plane accesses are 64-consecutive-lane x 16B.

// ---- P3: z2 = W2 h1 + b2 -> bf16 planes + fused BN2 stats ----------------
__global__ void HEAVY_BOUNDS k_z2(const float* __restrict__ x,
                                  const float* __restrict__ W2,
                                  const float* __restrict__ b2,
                                  float* __restrict__ ws,
                                  unsigned short* __restrict__ zb, int B) {
  const float* W1p = ws + WS_W1P;
  const float* c1 = ws + WS_C1;
  uint4* __restrict__ zp = (uint4*)zb;
  int tid = blockIdx.x * 256 + threadIdx.x;
  int nt = gridDim.x * 256;
  int lane = threadIdx.x & 63;
  float sacc = 0.f, qacc = 0.f;
  int iters = (B + nt - 1) / nt;
  for (int it = 0; it < iters; ++it) {
    int r = tid + it * nt;
    bool valid = (r < B);
    int rc = valid ? r : (B - 1);
    float w = valid ? 1.f : 0.f;
    float x0 = x[3 * rc], x1 = x[3 * rc + 1], x2 = x[3 * rc + 2];
    float h[64];
#pragma unroll
    for (int k = 0; k < 64; ++k) {
      float z = fmaf(W1p[3 * k + 2], x2,
                 fmaf(W1p[3 * k + 1], x1, fmaf(W1p[3 * k], x0, c1[k])));
      h[k] = fmaxf(z, 0.f);
    }
#pragma unroll 1
    for (int jb = 0; jb < 8; ++jb) {
      float z[8];
#pragma unroll
      for (int u = 0; u < 8; ++u) {
        int j = jb * 8 + u;
        z[u] = dot64(W2 + j * 64, h) + b2[j];
      }
      stat_rs8s(z, jb, lane, w, sacc, qacc);
      if (valid) {
        uint4 o;
        o.x = packbf2(z[0], z[1]); o.y = packbf2(z[2], z[3]);
        o.z = packbf2(z[4], z[5]); o.w = packbf2(z[6], z[7]);
        zp[(size_t)jb * B + r] = o;
      }
    }
  }
  block_combine_rc(sacc, qacc, ws + WS_SUM2, ws + WS_SSQ2);
}

// ---- P4/P6: BN scale/shift only ------------------------------------------
__global__ void k_fin_bn(const float* __restrict__ sum, const float* __restrict__ ssq,
                         const float* __restrict__ g, const float* __restrict__ be,
                         float* __restrict__ sOut, float* __restrict__ cOut, int B) {
  int j = threadIdx.x;  // 64
  float inv = 1.0f / (float)B;
  float mean = sum[j] * inv;
  float var = ssq[j] * inv - mean * mean;
  float s = g[j] * rsqrtf(var + kEps);
  sOut[j] = s;
  cOut[j] = fmaf(-s, mean, be[j]);
}

// ---- P5: z3 = W3 relu(s2*z2+c2) + b3, in place + fused BN3 stats ---------
__global__ void HEAVY_BOUNDS k_z3(const float* __restrict__ W3,
                                  const float* __restrict__ b3,
                                  float* __restrict__ ws,
                                  unsigned short* __restrict__ zb, int B) {
  const float* s2 = ws + FP_S2;
  const float* c2 = ws + FP_C2;
  uint4* __restrict__ zp = (uint4*)zb;
  int tid = blockIdx.x * 256 + threadIdx.x;
  int nt = gridDim.x * 256;
  int lane = threadIdx.x & 63;
  float sacc = 0.f, qacc = 0.f;
  int iters = (B + nt - 1) / nt;
  for (int it = 0; it < iters; ++it) {
    int r = tid + it * nt;
    bool valid = (r < B);
    int rc = valid ? r : (B - 1);
    float w = valid ? 1.f : 0.f;
    float h[64];
#pragma unroll
    for (int jb = 0; jb < 8; ++jb) {
      uint4 v = zp[(size_t)jb * B + rc];
      unpack2(v.x, h[jb * 8 + 0], h[jb * 8 + 1]);
      unpack2(v.y, h[jb * 8 + 2], h[jb * 8 + 3]);
      unpack2(v.z, h[jb * 8 + 4], h[jb * 8 + 5]);
      unpack2(v.w, h[jb * 8 + 6], h[jb * 8 + 7]);
    }
#pragma unroll
    for (int k = 0; k < 64; ++k)
      h[k] = fmaxf(fmaf(s2[k], h[k], c2[k]), 0.f);
#pragma unroll 1
    for (int jb = 0; jb < 8; ++jb) {
      float z[8];
#pragma unroll
      for (int u = 0; u < 8; ++u) {
        int j = jb * 8 + u;
        z[u] = dot64(W3 + j * 64, h) + b3[j];
      }
      stat_rs8s(z, jb, lane, w, sacc, qacc);
      if (valid) {
        uint4 o;
        o.x = packbf2(z[0], z[1]); o.y = packbf2(z[2], z[3]);
        o.z = packbf2(z[4], z[5]); o.w = packbf2(z[6], z[7]);
        zp[(size_t)jb * B + r] = o;
      }
    }
  }
  block_combine_rc(sacc, qacc, ws + WS_SUM3, ws + WS_SSQ3);
}

// ---- P7: h3 -> head -> FK -> out -----------------------------------------
__global__ void HEAVY_BOUNDS k_final_fast(const unsigned short* __restrict__ zb,
                                          const float* __restrict__ W4,
                                          const float* __restrict__ b4,
                                          const float* __restrict__ ws,
                                          float* __restrict__ out, int B) {
  const float* s3 = ws + FP_S3;
  const float* c3 = ws + FP_C3;
  const uint4* __restrict__ zp = (const uint4*)zb;
  int tid = blockIdx.x * 256 + threadIdx.x;
  int nt = gridDim.x * 256;
  for (int r = tid; r < B; r += nt) {
    float h[64];
#pragma unroll
    for (int jb = 0; jb < 8; ++jb) {
      uint4 v = zp[(size_t)jb * B + r];
      unpack2(v.x, h[jb * 8 + 0], h[jb * 8 + 1]);
      unpack2(v.y, h[jb * 8 + 2], h[jb * 8 + 3]);
      unpack2(v.z, h[jb * 8 + 4], h[jb * 8 + 5]);
      unpack2(v.w, h[jb * 8 + 6], h[jb * 8 + 7]);
    }
#pragma unroll
    for (int k = 0; k < 64; ++k)
      h[k] = fmaxf(fmaf(s3[k], h[k], c3[k]), 0.f);
    float t0 = dot64(W4, h) + b4[0];
    float t1 = dot64(W4 + 64, h) + b4[1];
    float t2 = dot64(W4 + 128, h) + b4[2];
    out[3 * r + 0] = t0;
    out[3 * r + 1] = t1;
    out[3 * r + 2] = t2;
    float s0, c0v, s1, c1v, s12, c12;
    sincosf(t0, &s0, &c0v);
    sincosf(t1, &s1, &c1v);
    sincosf(t1 + t2, &s12, &c12);
    float A = fmaf(0.115f, c12, 0.12f * c1v);
    size_t o2 = (size_t)3 * B + 3 * r;
    out[o2 + 0] = c0v * A;
    out[o2 + 1] = s0 * A;
    out[o2 + 2] = fmaf(0.115f, s12, 0.12f * s1);
  }
}

// ========================= FALLBACK (R1, verified) =========================

__device__ __forceinline__ void layer1_eval(const float* __restrict__ W1p,
                                            const float* __restrict__ c1,
                                            float x0, float x1, float x2,
                                            float h[64]) {
#pragma unroll
  for (int j = 0; j < 64; ++j) {
    float z = fmaf(W1p[3 * j + 2], x2,
               fmaf(W1p[3 * j + 1], x1, fmaf(W1p[3 * j], x0, c1[j])));
    h[j] = fmaxf(z, 0.f);
  }
}

__device__ __forceinline__ void dense_relu_rc(const float* __restrict__ Wp,
                                              const float* __restrict__ c,
                                              const float hin[64], float hout[64]) {
#pragma unroll
  for (int j = 0; j < 64; ++j)
    hout[j] = fmaxf(dot64(Wp + j * 64, hin) + c[j], 0.f);
}

__device__ __forceinline__ void dense_stats_rc(const float* __restrict__ W,
                                               const float* __restrict__ b,
                                               const float hin[64], int lane,
                                               float valid, float& accS, float& accQ) {
#pragma unroll 1
  for (int j = 0; j < 64; ++j) {
    float z = (dot64(W + j * 64, hin) + b[j]) * valid;
    float rs = wred64(z);
    float rq = wred64(z * z);
    accS += (lane == j) ? rs : 0.f;
    accQ += (lane == j) ? rq : 0.f;
  }
}

__global__ void __launch_bounds__(256) k_stats2_rc(const float* __restrict__ x,
                                                   const float* __restrict__ W2,
                                                   const float* __restrict__ b2,
                                                   float* __restrict__ ws, int B) {
  const float* W1p = ws + WS_W1P;
  const float* c1 = ws + WS_C1;
  int tid = blockIdx.x * 256 + threadIdx.x;
  int nt = gridDim.x * 256;
  int lane = threadIdx.x & 63;
  float accS = 0.f, accQ = 0.f;
  int iters = (B + nt - 1) / nt;
  for (int it = 0; it < iters; ++it) {
    int r = tid + it * nt;
    float valid = (r < B) ? 1.f : 0.f;
    int rc = (r < B) ? r : (B - 1);
    float h1[64];
    layer1_eval(W1p, c1, x[3 * rc], x[3 * rc + 1], x[3 * rc + 2], h1);
    dense_stats_rc(W2, b2, h1, lane, valid, accS, accQ);
  }
  block_combine_rc(accS, accQ, ws + WS_SUM2, ws + WS_SSQ2);
}

__global__ void k_fin_dense_rc(const float* __restrict__ W, const float* __restrict__ b,
                               const float* __restrict__ g, const float* __restrict__ be,
                               const float* __restrict__ sum, const float* __restrict__ ssq,
                               float* __restrict__ Wp, float* __restrict__ cc, int B) {
  int j = threadIdx.x;
  float inv = 1.0f / (float)B;
  float mean = sum[j] * inv;
  float var = ssq[j] * inv - mean * mean;
  float s = g[j] * rsqrtf(var + kEps);
  for (int k = 0; k < 64; ++k) Wp[j * 64 + k] = s * W[j * 64 + k];
  cc[j] = fmaf(s, b[j] - mean, be[j]);
}

__global__ void __launch_bounds__(256) k_stats3_rc(const float* __restrict__ x,
                                                   const float* __restrict__ W3,
                                                   const float* __restrict__ b3,
                                                   float* __restrict__ ws, int B) {
  const float* W1p = ws + WS_W1P;
  const float* c1 = ws + WS_C1;
  const float* W2p = ws + RC_W2P;
  const float* c2 = ws + RC_C2;
  int tid = blockIdx.x * 256 + threadIdx.x;
  int nt = gridDim.x * 256;
  int lane = threadIdx.x & 63;
  float accS = 0.f, accQ = 0.f;
  int iters = (B + nt - 1) / nt;
  for (int it = 0; it < iters; ++it) {
    int r = tid + it * nt;
    float valid = (r < B) ? 1.f : 0.f;
    int rc = (r < B) ? r : (B - 1);
    float h1[64], h2[64];
    layer1_eval(W1p, c1, x[3 * rc], x[3 * rc + 1], x[3 * rc + 2], h1);
    dense_relu_rc(W2p, c2, h1, h2);
    dense_stats_rc(W3, b3, h2, lane, valid, accS, accQ);
  }
  block_combine_rc(accS, accQ, ws + WS_SUM3, ws + WS_SSQ3);
}

__global__ void __launch_bounds__(256) k_final_rc(const float* __restrict__ x,
                                                  const float* __restrict__ W4,
                                                  const float* __restrict__ b4,
                                                  const float* __restrict__ ws,
                                                  float* __restrict__ out, int B) {
  const float* W1p = ws + WS_W1P;
  const float* c1 = ws + WS_C1;
  const float* W2p = ws + RC_W2P;
  const float* c2 = ws + RC_C2;
  const float* W3p = ws + RC_W3P;
  const float* c3 = ws + RC_C3;
  int tid = blockIdx.x * 256 + threadIdx.x;
  int nt = gridDim.x * 256;
  for (int r = tid; r < B; r += nt) {
    float h1[64], h2[64];
    layer1_eval(W1p, c1, x[3 * r], x[3 * r + 1], x[3 * r + 2], h1);
    dense_relu_rc(W2p, c2, h1, h2);
    float t0 = b4[0], t1 = b4[1], t2 = b4[2];
#pragma unroll 1
    for (int j = 0; j < 64; ++j) {
      float h3 = fmaxf(dot64(W3p + j * 64, h2) + c3[j], 0.f);
      t0 = fmaf(W4[j], h3, t0);
      t1 = fmaf(W4[64 + j], h3, t1);
      t2 = fmaf(W4[128 + j], h3, t2);
    }
    out[3 * r + 0] = t0;
    out[3 * r + 1] = t1;
    out[3 * r + 2] = t2;
    float s0, c0v, s1, c1v, s12, c12;
    sincosf(t0, &s0, &c0v);
    sincosf(t1, &s1, &c1v);
    sincosf(t1 + t2, &s12, &c12);
    float A = fmaf(0.115f, c12, 0.12f * c1v);
    size_t o2 = (size_t)3 * B + 3 * r;
    out[o2 + 0] = c0v * A;
    out[o2 + 1] = s0 * A;
    out[o2 + 2] = fmaf(0.115f, s12, 0.12f * s1);
  }
}

// ===========================================================================

extern "C" void kernel_launch(void* const* d_in, const int* in_sizes, int n_in,
                              void* d_out, int out_size, void* d_ws, size_t ws_size,
                              hipStream_t stream) {
  const float* x = (const float*)d_in[0];
  const float* W1 = (const float*)d_in[1];
  const float* b1 = (const float*)d_in[2];
  const float* g1 = (const float*)d_in[3];
  const float* be1 = (const float*)d_in[4];
  const float* W2 = (const float*)d_in[5];
  const float* b2 = (const float*)d_in[6];
  const float* g2 = (const float*)d_in[7];
  const float* be2 = (const float*)d_in[8];
  const float* W3 = (const float*)d_in[9];
  const float* b3 = (const float*)d_in[10];
  const float* g3 = (const float*)d_in[11];
  const float* be3 = (const float*)d_in[12];
  const float* W4 = (const float*)d_in[13];
  const float* b4 = (const float*)d_in[14];
  float* ws = (float*)d_ws;
  float* out = (float*)d_out;
  int B = in_sizes[0] / 3;

  hipMemsetAsync(d_ws, 0, 272 * sizeof(float), stream);

  const int blocks = 1024, thr = 256;
  const int zblocks = 2048;
  size_t need = 65536 + (size_t)B * 64 * 2;

  k_stats_x<<<blocks, thr, 0, stream>>>(x, ws, B);
  k_fin1<<<1, 64, 0, stream>>>(W1, b1, g1, be1, ws, B);

  if (ws_size >= need) {
    unsigned short* zb = (unsigned short*)ws + ZB_U16;
    k_z2<<<zblocks, thr, 0, stream>>>(x, W2, b2, ws, zb, B);
    k_fin_bn<<<1, 64, 0, stream>>>(ws + WS_SUM2, ws + WS_SSQ2, g2, be2,
                                   ws + FP_S2, ws + FP_C2, B);
    k_z3<<<zblocks, thr, 0, stream>>>(W3, b3, ws, zb, B);
    k_fin_bn<<<1, 64, 0, stream>>>(ws + WS_SUM3, ws + WS_SSQ3, g3, be3,
                                   ws + FP_S3, ws + FP_C3, B);
    k_final_fast<<<zblocks, thr, 0, stream>>>(zb, W4, b4, ws, out, B);
  } else {
    k_stats2_rc<<<blocks, thr, 0, stream>>>(x, W2, b2, ws, B);
    k_fin_dense_rc<<<1, 64, 0, stream>>>(W2, b2, g2, be2, ws + WS_SUM2, ws + WS_SSQ2,
                                         ws + RC_W2P, ws + RC_C2, B);
    k_stats3_rc<<<blocks, thr, 0, stream>>>(x, W3, b3, ws, B);
    k_fin_dense_rc<<<1, 64, 0, stream>>>(W3, b3, g3, be3, ws + WS_SUM3, ws + WS_SSQ3,
                                         ws + RC_W3P, ws + RC_C3, B);
    k_final_rc<<<blocks, thr, 0, stream>>>(x, W4, b4, ws, out, B);
  }
}